// Round 3
// baseline (954.440 us; speedup 1.0000x reference)
//
#include <hip/hip_runtime.h>
#include <stdint.h>

#define NTOK 196
#define KCL 49
#define IMG 224
#define IMG2 (224*224)

// ---------------- JAX threefry2x32 (20 rounds), host+device ----------------
__host__ __device__ __forceinline__ void tf2x32(uint32_t k0, uint32_t k1,
    uint32_t x0, uint32_t x1, uint32_t* o0, uint32_t* o1) {
  uint32_t ks2 = k0 ^ k1 ^ 0x1BD11BDAu;
#define TFR(r) { x0 += x1; x1 = (x1 << r) | (x1 >> (32 - r)); x1 ^= x0; }
  x0 += k0; x1 += k1;
  TFR(13) TFR(15) TFR(26) TFR(6)
  x0 += k1; x1 += ks2 + 1u;
  TFR(17) TFR(29) TFR(16) TFR(24)
  x0 += ks2; x1 += k0 + 2u;
  TFR(13) TFR(15) TFR(26) TFR(6)
  x0 += k0; x1 += k1 + 3u;
  TFR(17) TFR(29) TFR(16) TFR(24)
  x0 += k1; x1 += ks2 + 4u;
  TFR(13) TFR(15) TFR(26) TFR(6)
  x0 += ks2; x1 += k0 + 5u;
#undef TFR
  *o0 = x0; *o1 = x1;
}

// jax.random.uniform f32 bits, PARTITIONABLE threefry (jax >= 0.5 default):
// per flat index j: (o0,o1) = threefry2x32(key, (hi32(j), lo32(j))); bits = o0 ^ o1
__device__ __forceinline__ float jax_uniform(uint32_t k0, uint32_t k1, uint32_t j) {
  uint32_t o0, o1;
  tf2x32(k0, k1, 0u, j, &o0, &o1);
  uint32_t bits = o0 ^ o1;
  return __uint_as_float((bits >> 9) | 0x3f800000u) - 1.0f;
}

// ---------------- K0: per-token sum of squares (fp64) ----------------
__global__ void __launch_bounds__(256) k_sq(const float* __restrict__ x,
                                            double* __restrict__ sq, int B) {
  int wave = blockIdx.x * 4 + (threadIdx.x >> 6);
  int lane = threadIdx.x & 63;
  if (wave >= B * NTOK) return;
  int b = wave / NTOK, n = wave % NTOK;
  int p1 = n / 14, p2 = n % 14;
  const float* xb = x + (size_t)b * 3 * IMG2;
  int rowbase = (p1 * 16) * IMG + p2 * 16;
  double acc = 0.0;
#pragma unroll
  for (int q = 0; q < 12; ++q) {
    int f = lane + q * 64;               // f = c*256 + h*16 + w (permuted feature order)
    int c = f >> 8, h = (f >> 4) & 15, w = f & 15;
    float v = xb[c * IMG2 + rowbase + h * IMG + w];
    acc += (double)v * (double)v;
  }
#pragma unroll
  for (int off = 32; off; off >>= 1) acc += __shfl_down(acc, off);
  if (lane == 0) sq[wave] = acc;
}

// ---------------- K1: Gram -> fp64 dist matrix + per-batch max ----------------
__global__ void __launch_bounds__(256) k_dist(const float* __restrict__ x,
    const double* __restrict__ sq, double* __restrict__ dist,
    unsigned long long* __restrict__ dmax) {
  int b = blockIdx.z;
  int n0 = blockIdx.y * 32, m0 = blockIdx.x * 32;
  int tid = threadIdx.x;
  int tx = tid & 15, ty = tid >> 4;
  __shared__ float As[32][33], Bs[32][33];
  __shared__ int rbN[32], rbM[32];
  __shared__ double red[256];
  if (tid < 32) {
    int n = n0 + tid;
    rbN[tid] = (n < NTOK) ? ((n / 14) * 16) * IMG + (n % 14) * 16 : 0;
  } else if (tid < 64) {
    int m = m0 + (tid - 32);
    rbM[tid - 32] = (m < NTOK) ? ((m / 14) * 16) * IMG + (m % 14) * 16 : 0;
  }
  __syncthreads();
  const float* xb = x + (size_t)b * 3 * IMG2;
  double a00 = 0, a01 = 0, a10 = 0, a11 = 0;
  for (int kc = 0; kc < 768; kc += 32) {
#pragma unroll
    for (int q = 0; q < 4; ++q) {
      int e = tid + q * 256;
      int i = e >> 5, j = e & 31;
      int f = kc + j;
      int c = f >> 8, h = (f >> 4) & 15, w = f & 15;
      int off = c * IMG2 + h * IMG + w;
      As[i][j] = xb[off + rbN[i]];
      Bs[i][j] = xb[off + rbM[i]];
    }
    __syncthreads();
#pragma unroll
    for (int kk = 0; kk < 32; ++kk) {
      double x0 = (double)As[ty][kk], x1 = (double)As[ty + 16][kk];
      double y0 = (double)Bs[tx][kk], y1 = (double)Bs[tx + 16][kk];
      a00 += x0 * y0;
      a01 += x0 * y1;
      a10 += x1 * y0;
      a11 += x1 * y1;
    }
    __syncthreads();
  }
  const double SQRT768 = sqrt(768.0);
  const double* sqb = sq + b * NTOK;
  double* Db = dist + (size_t)b * NTOK * NTOK;
  double accs[2][2] = {{a00, a01}, {a10, a11}};
  double localmax = 0.0;
#pragma unroll
  for (int ai = 0; ai < 2; ++ai)
#pragma unroll
    for (int bj = 0; bj < 2; ++bj) {
      int n = n0 + ty + ai * 16, m = m0 + tx + bj * 16;
      if (n < NTOK && m < NTOK) {
        double d2 = sqb[n] + sqb[m] - 2.0 * accs[ai][bj];
        double d = sqrt(d2 > 0.0 ? d2 : 0.0) / SQRT768;
        Db[n * NTOK + m] = d;
        localmax = localmax > d ? localmax : d;
      }
    }
  red[tid] = localmax;
  __syncthreads();
  for (int s = 128; s; s >>= 1) {
    if (tid < s && red[tid + s] > red[tid]) red[tid] = red[tid + s];
    __syncthreads();
  }
  if (tid == 0) atomicMax(&dmax[b], (unsigned long long)__double_as_longlong(red[0]));
}

// ---------------- K2: per-batch clustering (one block per batch), fp64 ----------------
__global__ void __launch_bounds__(256) k_cluster(const double* __restrict__ dist,
    const unsigned long long* __restrict__ dmax, int* __restrict__ out,
    uint32_t kd0, uint32_t kd1, uint32_t kn0, uint32_t kn1, int B) {
  int b = blockIdx.x;
  int tid = threadIdx.x;
  const double* Db = dist + (size_t)b * NTOK * NTOK;
  __shared__ double dens[NTOK];
  __shared__ double score[NTOK];
  __shared__ int center[KCL];
  __shared__ short center_of[NTOK];
  __shared__ double rv[256];
  __shared__ int ri[256];
  __shared__ unsigned long long bkey[KCL];
  double dmaxv = __longlong_as_double((long long)dmax[b]);

  // P1: kNN(5) density (fp64) + threefry noise*1e-6
  if (tid < NTOK) {
    const double* row = Db + tid * NTOK;
    double nb0 = 1e300, nb1 = 1e300, nb2 = 1e300, nb3 = 1e300, nb4 = 1e300;
    for (int m = 0; m < NTOK; ++m) {
      double v = row[m];
      if (v < nb4) {
        nb4 = v;
        if (nb4 < nb3) { double t = nb3; nb3 = nb4; nb4 = t;
          if (nb3 < nb2) { t = nb2; nb2 = nb3; nb3 = t;
            if (nb2 < nb1) { t = nb1; nb1 = nb2; nb2 = t;
              if (nb1 < nb0) { t = nb0; nb0 = nb1; nb1 = t; } } } }
      }
    }
    double acc = nb0 * nb0 + nb1 * nb1 + nb2 * nb2 + nb3 * nb3 + nb4 * nb4;
    double mean = acc / 5.0;
    double d = exp(-mean);
    double u = (double)jax_uniform(kd0, kd1, (uint32_t)(b * NTOK + tid));
    dens[tid] = d + u * 1e-6;
  }
  __syncthreads();

  // P2: dmin over strictly-higher-density tokens (filler = dist_max), score
  if (tid < NTOK) {
    const double* row = Db + tid * NTOK;
    double dn = dens[tid];
    double v = dmaxv;
    for (int m = 0; m < NTOK; ++m)
      if (dens[m] > dn) { double r = row[m]; v = r < v ? r : v; }
    score[tid] = v * dens[tid];
  }
  __syncthreads();

  // P3: iterative top-49 (ties -> lower index), order = cluster id
  for (int k = 0; k < KCL; ++k) {
    double v = -1e300; int idx = 0;
    if (tid < NTOK && score[tid] >= 0.0) { v = score[tid]; idx = tid; }
    rv[tid] = v; ri[tid] = idx;
    __syncthreads();
    for (int s = 128; s; s >>= 1) {
      if (tid < s) {
        double ov = rv[tid + s]; int oi = ri[tid + s];
        if (ov > rv[tid] || (ov == rv[tid] && oi < ri[tid])) { rv[tid] = ov; ri[tid] = oi; }
      }
      __syncthreads();
    }
    if (tid == 0) {
      int n = ri[0];
      center[k] = n;
      score[n] = -1.0;  // mark taken
    }
    __syncthreads();
  }

  // P4: assign to nearest center (ties -> lower k), centers self-assign
  if (tid < NTOK) center_of[tid] = -1;
  __syncthreads();
  if (tid < KCL) { center_of[center[tid]] = (short)tid; bkey[tid] = 0ULL; }
  __syncthreads();
  int mycl = 0;
  if (tid < NTOK) {
    double best = 1e300; int bk = 0;
    for (int k = 0; k < KCL; ++k) {
      double d = Db[center[k] * NTOK + tid];
      if (d < best) { best = d; bk = k; }
    }
    short co = center_of[tid];
    if (co >= 0) bk = co;
    mycl = bk;
  }
  __syncthreads();

  // P5: representative = token at position cum_k-1 of stable sort by fl32(k+u).
  // Equivalent: per-cluster max of f32 key (k+u), ties -> larger token index.
  if (tid < NTOK) {
    float u = jax_uniform(kn0, kn1, (uint32_t)(b * NTOK + tid));
    float keyf = (float)mycl + u;   // single f32 add, round-nearest (matches jax)
    unsigned long long key =
        ((unsigned long long)__float_as_uint(keyf) << 8) | (unsigned)tid;
    atomicMax(&bkey[mycl], key);
  }
  __syncthreads();
  if (tid < KCL) out[b * KCL + tid] = (int)(bkey[tid] & 0xFFu);
}

// ---------------- launch ----------------
extern "C" void kernel_launch(void* const* d_in, const int* in_sizes, int n_in,
                              void* d_out, int out_size, void* d_ws, size_t ws_size,
                              hipStream_t stream) {
  const float* x = (const float*)d_in[0];
  int B = in_sizes[0] / (3 * IMG2);           // 256
  double* dist = (double*)d_ws;
  size_t distBytes = (size_t)B * NTOK * NTOK * sizeof(double);
  double* sq = (double*)((char*)d_ws + distBytes);
  unsigned long long* dmax =
      (unsigned long long*)((char*)sq + (size_t)B * NTOK * sizeof(double));
  int* out = (int*)d_out;

  // derived threefry keys: key(1) = (0,1); fold_in(key,0) and fold_in(key,1)
  // (fold_in calls threefry_2x32 directly; unaffected by partitionable flag)
  uint32_t kd0, kd1, kn0, kn1;
  tf2x32(0u, 1u, 0u, 0u, &kd0, &kd1);
  tf2x32(0u, 1u, 0u, 1u, &kn0, &kn1);

  hipMemsetAsync(dmax, 0, B * sizeof(unsigned long long), stream);
  int totalTok = B * NTOK;
  k_sq<<<dim3((totalTok + 3) / 4), dim3(256), 0, stream>>>(x, sq, B);
  k_dist<<<dim3(7, 7, B), dim3(256), 0, stream>>>(x, sq, dist, dmax);
  k_cluster<<<dim3(B), dim3(256), 0, stream>>>(dist, dmax, out, kd0, kd1, kn0, kn1, B);
}

// Round 5
// 917.053 us; speedup vs baseline: 1.0408x; 1.0408x over previous
//
#include <hip/hip_runtime.h>
#include <stdint.h>

#define NTOK 196
#define KCL 49
#define IMG 224
#define IMG2 (224*224)
#define KB 64
#define LDP 65   // KB+1 padding for bank-conflict-free ds_read_b64

typedef double f64x4 __attribute__((ext_vector_type(4)));

// ---------------- JAX threefry2x32 (20 rounds), host+device ----------------
__host__ __device__ __forceinline__ void tf2x32(uint32_t k0, uint32_t k1,
    uint32_t x0, uint32_t x1, uint32_t* o0, uint32_t* o1) {
  uint32_t ks2 = k0 ^ k1 ^ 0x1BD11BDAu;
#define TFR(r) { x0 += x1; x1 = (x1 << r) | (x1 >> (32 - r)); x1 ^= x0; }
  x0 += k0; x1 += k1;
  TFR(13) TFR(15) TFR(26) TFR(6)
  x0 += k1; x1 += ks2 + 1u;
  TFR(17) TFR(29) TFR(16) TFR(24)
  x0 += ks2; x1 += k0 + 2u;
  TFR(13) TFR(15) TFR(26) TFR(6)
  x0 += k0; x1 += k1 + 3u;
  TFR(17) TFR(29) TFR(16) TFR(24)
  x0 += k1; x1 += ks2 + 4u;
  TFR(13) TFR(15) TFR(26) TFR(6)
  x0 += ks2; x1 += k0 + 5u;
#undef TFR
  *o0 = x0; *o1 = x1;
}

// jax.random.uniform f32 bits, PARTITIONABLE threefry (jax >= 0.5 default):
// per flat index j: (o0,o1) = threefry2x32(key, (hi32(j), lo32(j))); bits = o0 ^ o1
__device__ __forceinline__ float jax_uniform(uint32_t k0, uint32_t k1, uint32_t j) {
  uint32_t o0, o1;
  tf2x32(k0, k1, 0u, j, &o0, &o1);
  uint32_t bits = o0 ^ o1;
  return __uint_as_float((bits >> 9) | 0x3f800000u) - 1.0f;
}

// ---------------- K0: per-token sum of squares (fp64) ----------------
__global__ void __launch_bounds__(256) k_sq(const float* __restrict__ x,
                                            double* __restrict__ sq, int B) {
  int wave = blockIdx.x * 4 + (threadIdx.x >> 6);
  int lane = threadIdx.x & 63;
  if (wave >= B * NTOK) return;
  int b = wave / NTOK, n = wave % NTOK;
  int p1 = n / 14, p2 = n % 14;
  const float* xb = x + (size_t)b * 3 * IMG2;
  int rowbase = (p1 * 16) * IMG + p2 * 16;
  double acc = 0.0;
#pragma unroll
  for (int q = 0; q < 12; ++q) {
    int f = lane + q * 64;               // f = c*256 + h*16 + w (permuted feature order)
    int c = f >> 8, h = (f >> 4) & 15, w = f & 15;
    float v = xb[c * IMG2 + rowbase + h * IMG + w];
    acc += (double)v * (double)v;
  }
#pragma unroll
  for (int off = 32; off; off >>= 1) acc += __shfl_down(acc, off);
  if (lane == 0) sq[wave] = acc;
}

// ---------------- staging: 32 tokens x 64 features (f32 global -> f64 LDS) ----------------
__device__ __forceinline__ void stage_tile(const float* __restrict__ xb,
    const int* rbN, const int* rbM,
    double (*As)[LDP], double (*Bs)[LDP], int srow, int sfo, int kc) {
  int f0 = kc + sfo;
  int c = f0 >> 8, h = (f0 >> 4) & 15, w0 = f0 & 15;
  int goff = c * IMG2 + h * IMG + w0;
  const float* pa = xb + goff + rbN[srow];
  const float* pb = xb + goff + rbM[srow];
  float4 va0 = *(const float4*)(pa);
  float4 va1 = *(const float4*)(pa + 4);
  float4 vb0 = *(const float4*)(pb);
  float4 vb1 = *(const float4*)(pb + 4);
  __syncthreads();                 // previous phase done reading LDS
  As[srow][sfo + 0] = (double)va0.x; As[srow][sfo + 1] = (double)va0.y;
  As[srow][sfo + 2] = (double)va0.z; As[srow][sfo + 3] = (double)va0.w;
  As[srow][sfo + 4] = (double)va1.x; As[srow][sfo + 5] = (double)va1.y;
  As[srow][sfo + 6] = (double)va1.z; As[srow][sfo + 7] = (double)va1.w;
  Bs[srow][sfo + 0] = (double)vb0.x; Bs[srow][sfo + 1] = (double)vb0.y;
  Bs[srow][sfo + 2] = (double)vb0.z; Bs[srow][sfo + 3] = (double)vb0.w;
  Bs[srow][sfo + 4] = (double)vb1.x; Bs[srow][sfo + 5] = (double)vb1.y;
  Bs[srow][sfo + 6] = (double)vb1.z; Bs[srow][sfo + 7] = (double)vb1.w;
  __syncthreads();                 // tile staged
}

// ---------------- K1: f64-MFMA Gram with self-verification + scalar fallback ----------
// grid: 8 xcd * 32 batch-groups * 49 tiles = 12544 blocks of 256
__global__ void __launch_bounds__(256) k_dist_mfma(const float* __restrict__ x,
    const double* __restrict__ sq, double* __restrict__ dist,
    unsigned long long* __restrict__ dmax) {
  int bid = blockIdx.x;
  int xcd = bid & 7;
  int s = bid >> 3;                 // 0..1567
  int b = xcd + 8 * (s / 49);       // batch: keeps each batch's blocks on one XCD
  int t = s % 49;
  int ti = t / 7, tj = t % 7;
  int n0b = ti * 32, m0b = tj * 32;
  int tid = threadIdx.x;

  __shared__ double As[32][LDP];
  __shared__ double Bs[32][LDP];
  __shared__ int rbN[32], rbM[32];
  __shared__ double prsh[4];
  __shared__ int okf;

  if (tid < 32) {
    int n = n0b + tid; n = n < NTOK ? n : NTOK - 1;
    rbN[tid] = (n / 14) * 16 * IMG + (n % 14) * 16;
  } else if (tid < 64) {
    int m = m0b + (tid - 32); m = m < NTOK ? m : NTOK - 1;
    rbM[tid - 32] = (m / 14) * 16 * IMG + (m % 14) * 16;
  }
  __syncthreads();

  const float* xb = x + (size_t)b * 3 * IMG2;
  int srow = tid >> 3;              // staging row 0..31
  int sfo  = (tid & 7) * 8;         // staging feature offset 0..56
  int lane = tid & 63;
  int wid  = tid >> 6;
  int wi = wid >> 1, wj = wid & 1;  // wave quadrant in 32x32 tile
  int aq = lane >> 4;               // assumed A/B k sub-index 0..3
  const double* Ap = &As[0][0];
  const double* Bp = &Bs[0][0];
  int abase = (wi * 16 + (lane & 15)) * LDP + aq;
  int bbase = (wj * 16 + (lane & 15)) * LDP + aq;

  f64x4 acc = {0.0, 0.0, 0.0, 0.0};
  double probe = 0.0;
  // probe dots: tid0 = A0.B0, tid1 = A1.B0, tid2 = A4.B0, tid3 = A0.B1
  int par = (tid == 2) ? 4 : ((tid == 1) ? 1 : 0);
  int pbr = (tid == 3) ? 1 : 0;

  for (int kc = 0; kc < 768; kc += KB) {
    stage_tile(xb, rbN, rbM, As, Bs, srow, sfo, kc);
#pragma unroll
    for (int k = 0; k < KB; k += 4)
      acc = __builtin_amdgcn_mfma_f64_16x16x4f64(Ap[abase + k], Bp[bbase + k], acc, 0, 0, 0);
    if (tid < 4) {
      const double* ar = &As[par][0];
      const double* br = &Bs[pbr][0];
      for (int j = 0; j < KB; ++j) probe += ar[j] * br[j];
    }
  }
  if (tid < 4) prsh[tid] = probe;
  __syncthreads();
  if (tid == 0) {
    // thread 0 is wave 0 (wi=wj=0), lane 0 (col 0, aq=0):
    //   layout P1: acc[i] = dot(row i,  col 0)
    //   layout P2: acc[i] = dot(row 4i, col 0)
    double tol = 1e-6 * (1.0 + fabs(prsh[0]));
    int ok0  = fabs(prsh[0] - acc[0]) <= tol;
    int okP1 = ok0 && (fabs(prsh[1] - acc[1]) <= tol);
    int okP2 = ok0 && (fabs(prsh[2] - acc[1]) <= tol);
    okf = okP1 ? 1 : (okP2 ? 2 : 0);
  }
  __syncthreads();
  int mode = okf;

  double (*Dt)[33] = (double(*)[33])(&As[0][0]);   // raw-dot tile (aliases As)

  if (mode) {
    // MFMA attribution verified: scatter acc to Dt per detected layout
#pragma unroll
    for (int i = 0; i < 4; ++i) {
      int lr = (mode == 1) ? (aq * 4 + i) : (aq + 4 * i);
      Dt[wi * 16 + lr][wj * 16 + (lane & 15)] = acc[i];
    }
  } else {
    // fallback: recompute tile with scalar f64 (proven round-3 logic)
    double s00 = 0, s01 = 0, s10 = 0, s11 = 0;
    int ty = tid >> 4, tx = tid & 15;
    for (int kc = 0; kc < 768; kc += KB) {
      stage_tile(xb, rbN, rbM, As, Bs, srow, sfo, kc);
      for (int j = 0; j < KB; ++j) {
        double a0 = As[ty][j], a1 = As[ty + 16][j];
        double b0 = Bs[tx][j], b1 = Bs[tx + 16][j];
        s00 += a0 * b0; s01 += a0 * b1; s10 += a1 * b0; s11 += a1 * b1;
      }
    }
    __syncthreads();               // all scalar reads of As done before Dt overwrite
    Dt[ty][tx] = s00;           Dt[ty][tx + 16] = s01;
    Dt[ty + 16][tx] = s10;      Dt[ty + 16][tx + 16] = s11;
  }
  __syncthreads();

  // Phase B: dot -> dist, per-batch max, coalesced write
  const double* sqb = sq + b * NTOK;
  const double SQ768 = sqrt(768.0);
  int lr2 = tid >> 3, lc0 = (tid & 7) * 4;
  double dv[4];
  double lmax = 0.0;
#pragma unroll
  for (int j = 0; j < 4; ++j) {
    int n = n0b + lr2, m = m0b + lc0 + j;
    int nn = n < NTOK ? n : NTOK - 1, mm = m < NTOK ? m : NTOK - 1;
    double dot = Dt[lr2][lc0 + j];
    double d2 = sqb[nn] + sqb[mm] - 2.0 * dot;
    double d = sqrt(d2 > 0.0 ? d2 : 0.0) / SQ768;
    dv[j] = d;
    lmax = lmax > d ? lmax : d;
  }
  double* red = (double*)(&Bs[0][0]);
  red[tid] = lmax;
  __syncthreads();
  for (int st = 128; st; st >>= 1) {
    if (tid < st) { double o = red[tid + st]; if (o > red[tid]) red[tid] = o; }
    __syncthreads();
  }
  if (tid == 0) atomicMax(&dmax[b], (unsigned long long)__double_as_longlong(red[0]));

  double* Db = dist + (size_t)b * NTOK * NTOK;
  {
    int n = n0b + lr2, m0 = m0b + lc0;
    if (n < NTOK && m0 < NTOK) {
      if (m0 + 3 < NTOK) {
        f64x4 v = {dv[0], dv[1], dv[2], dv[3]};
        *(f64x4*)(Db + (size_t)n * NTOK + m0) = v;
      } else {
#pragma unroll
        for (int j = 0; j < 4; ++j)
          if (m0 + j < NTOK) Db[(size_t)n * NTOK + m0 + j] = dv[j];
      }
    }
  }
}

// ---------------- K2: per-batch clustering (one block per batch), fp64 ----------------
__global__ void __launch_bounds__(256) k_cluster(const double* __restrict__ dist,
    const unsigned long long* __restrict__ dmax, int* __restrict__ out,
    uint32_t kd0, uint32_t kd1, uint32_t kn0, uint32_t kn1, int B) {
  int b = blockIdx.x;
  int tid = threadIdx.x;
  const double* Db = dist + (size_t)b * NTOK * NTOK;
  __shared__ double dens[NTOK];
  __shared__ double score[NTOK];
  __shared__ int center[KCL];
  __shared__ short center_of[NTOK];
  __shared__ double rv[256];
  __shared__ int ri[256];
  __shared__ unsigned long long bkey[KCL];
  double dmaxv = __longlong_as_double((long long)dmax[b]);

  // P1: kNN(5) density (fp64) + threefry noise*1e-6
  if (tid < NTOK) {
    const double* row = Db + tid * NTOK;
    double nb0 = 1e300, nb1 = 1e300, nb2 = 1e300, nb3 = 1e300, nb4 = 1e300;
    for (int m = 0; m < NTOK; ++m) {
      double v = row[m];
      if (v < nb4) {
        nb4 = v;
        if (nb4 < nb3) { double t = nb3; nb3 = nb4; nb4 = t;
          if (nb3 < nb2) { t = nb2; nb2 = nb3; nb3 = t;
            if (nb2 < nb1) { t = nb1; nb1 = nb2; nb2 = t;
              if (nb1 < nb0) { t = nb0; nb0 = nb1; nb1 = t; } } } }
      }
    }
    double acc = nb0 * nb0 + nb1 * nb1 + nb2 * nb2 + nb3 * nb3 + nb4 * nb4;
    double mean = acc / 5.0;
    double d = exp(-mean);
    double u = (double)jax_uniform(kd0, kd1, (uint32_t)(b * NTOK + tid));
    dens[tid] = d + u * 1e-6;
  }
  __syncthreads();

  // P2: dmin over strictly-higher-density tokens (filler = dist_max), score
  if (tid < NTOK) {
    const double* row = Db + tid * NTOK;
    double dn = dens[tid];
    double v = dmaxv;
    for (int m = 0; m < NTOK; ++m)
      if (dens[m] > dn) { double r = row[m]; v = r < v ? r : v; }
    score[tid] = v * dens[tid];
  }
  __syncthreads();

  // P3: iterative top-49 (ties -> lower index), order = cluster id
  for (int k = 0; k < KCL; ++k) {
    double v = -1e300; int idx = 0;
    if (tid < NTOK && score[tid] >= 0.0) { v = score[tid]; idx = tid; }
    rv[tid] = v; ri[tid] = idx;
    __syncthreads();
    for (int st = 128; st; st >>= 1) {
      if (tid < st) {
        double ov = rv[tid + st]; int oi = ri[tid + st];
        if (ov > rv[tid] || (ov == rv[tid] && oi < ri[tid])) { rv[tid] = ov; ri[tid] = oi; }
      }
      __syncthreads();
    }
    if (tid == 0) {
      int n = ri[0];
      center[k] = n;
      score[n] = -1.0;  // mark taken
    }
    __syncthreads();
  }

  // P4: assign to nearest center (ties -> lower k), centers self-assign
  if (tid < NTOK) center_of[tid] = -1;
  __syncthreads();
  if (tid < KCL) { center_of[center[tid]] = (short)tid; bkey[tid] = 0ULL; }
  __syncthreads();
  int mycl = 0;
  if (tid < NTOK) {
    double best = 1e300; int bk = 0;
    for (int k = 0; k < KCL; ++k) {
      double d = Db[center[k] * NTOK + tid];
      if (d < best) { best = d; bk = k; }
    }
    short co = center_of[tid];
    if (co >= 0) bk = co;
    mycl = bk;
  }
  __syncthreads();

  // P5: representative = per-cluster max of f32 key (k+u), ties -> larger token index
  if (tid < NTOK) {
    float u = jax_uniform(kn0, kn1, (uint32_t)(b * NTOK + tid));
    float keyf = (float)mycl + u;   // single f32 add, round-nearest (matches jax)
    unsigned long long key =
        ((unsigned long long)__float_as_uint(keyf) << 8) | (unsigned)tid;
    atomicMax(&bkey[mycl], key);
  }
  __syncthreads();
  if (tid < KCL) out[b * KCL + tid] = (int)(bkey[tid] & 0xFFu);
}

// ---------------- launch ----------------
extern "C" void kernel_launch(void* const* d_in, const int* in_sizes, int n_in,
                              void* d_out, int out_size, void* d_ws, size_t ws_size,
                              hipStream_t stream) {
  const float* x = (const float*)d_in[0];
  int B = in_sizes[0] / (3 * IMG2);           // 256
  double* dist = (double*)d_ws;
  size_t distBytes = (size_t)B * NTOK * NTOK * sizeof(double);
  double* sq = (double*)((char*)d_ws + distBytes);
  unsigned long long* dmax =
      (unsigned long long*)((char*)sq + (size_t)B * NTOK * sizeof(double));
  int* out = (int*)d_out;

  uint32_t kd0, kd1, kn0, kn1;
  tf2x32(0u, 1u, 0u, 0u, &kd0, &kd1);
  tf2x32(0u, 1u, 0u, 1u, &kn0, &kn1);

  hipMemsetAsync(dmax, 0, B * sizeof(unsigned long long), stream);
  int totalTok = B * NTOK;
  k_sq<<<dim3((totalTok + 3) / 4), dim3(256), 0, stream>>>(x, sq, B);
  k_dist_mfma<<<dim3(8 * 32 * 49), dim3(256), 0, stream>>>(x, sq, dist, dmax);
  k_cluster<<<dim3(B), dim3(256), 0, stream>>>(dist, dmax, out, kd0, kd1, kn0, kn1, B);
}

// Round 6
// 641.944 us; speedup vs baseline: 1.4868x; 1.4286x over previous
//
#include <hip/hip_runtime.h>
#include <stdint.h>

#define NTOK 196
#define KCL 49
#define IMG 224
#define IMG2 (224*224)
#define KB 64
#define LDP 65   // KB+1 padding

typedef double f64x4 __attribute__((ext_vector_type(4)));

// ---------------- JAX threefry2x32 (20 rounds), host+device ----------------
__host__ __device__ __forceinline__ void tf2x32(uint32_t k0, uint32_t k1,
    uint32_t x0, uint32_t x1, uint32_t* o0, uint32_t* o1) {
  uint32_t ks2 = k0 ^ k1 ^ 0x1BD11BDAu;
#define TFR(r) { x0 += x1; x1 = (x1 << r) | (x1 >> (32 - r)); x1 ^= x0; }
  x0 += k0; x1 += k1;
  TFR(13) TFR(15) TFR(26) TFR(6)
  x0 += k1; x1 += ks2 + 1u;
  TFR(17) TFR(29) TFR(16) TFR(24)
  x0 += ks2; x1 += k0 + 2u;
  TFR(13) TFR(15) TFR(26) TFR(6)
  x0 += k0; x1 += k1 + 3u;
  TFR(17) TFR(29) TFR(16) TFR(24)
  x0 += k1; x1 += ks2 + 4u;
  TFR(13) TFR(15) TFR(26) TFR(6)
  x0 += ks2; x1 += k0 + 5u;
#undef TFR
  *o0 = x0; *o1 = x1;
}

// jax.random.uniform f32 bits, PARTITIONABLE threefry (jax >= 0.5 default)
__device__ __forceinline__ float jax_uniform(uint32_t k0, uint32_t k1, uint32_t j) {
  uint32_t o0, o1;
  tf2x32(k0, k1, 0u, j, &o0, &o1);
  uint32_t bits = o0 ^ o1;
  return __uint_as_float((bits >> 9) | 0x3f800000u) - 1.0f;
}

// ---------------- K0: per-token sum of squares (fp64) ----------------
__global__ void __launch_bounds__(256) k_sq(const float* __restrict__ x,
                                            double* __restrict__ sq, int B) {
  int wave = blockIdx.x * 4 + (threadIdx.x >> 6);
  int lane = threadIdx.x & 63;
  if (wave >= B * NTOK) return;
  int b = wave / NTOK, n = wave % NTOK;
  int p1 = n / 14, p2 = n % 14;
  const float* xb = x + (size_t)b * 3 * IMG2;
  int rowbase = (p1 * 16) * IMG + p2 * 16;
  double acc = 0.0;
#pragma unroll
  for (int q = 0; q < 12; ++q) {
    int f = lane + q * 64;
    int c = f >> 8, h = (f >> 4) & 15, w = f & 15;
    float v = xb[c * IMG2 + rowbase + h * IMG + w];
    acc += (double)v * (double)v;
  }
#pragma unroll
  for (int off = 32; off; off >>= 1) acc += __shfl_down(acc, off);
  if (lane == 0) sq[wave] = acc;
}

// ---------------- K1: f64-MFMA Gram, triangle+mirror, reg double-buffer ----------
// grid: 8 xcd * 32 batch-groups * 28 triangle-tiles = 7168 blocks of 256
__global__ void __launch_bounds__(256) k_dist_mfma(const float* __restrict__ x,
    const double* __restrict__ sq, double* __restrict__ dist,
    unsigned long long* __restrict__ dmax) {
  int bid = blockIdx.x;
  int xcd = bid & 7;
  int s = bid >> 3;                 // 0..895
  int b = xcd + 8 * (s / 28);
  int t = s % 28;
  int ti = 0, rem = t, rl = 7;
  while (rem >= rl) { rem -= rl; rl--; ti++; }
  int tj = ti + rem;                // ti <= tj
  int n0b = ti * 32, m0b = tj * 32;
  int tid = threadIdx.x;

  __shared__ double As[32][LDP];
  __shared__ double Bs[32][LDP];
  __shared__ int rbN[32], rbM[32];
  __shared__ double prsh[3];
  __shared__ int okf;

  if (tid < 32) {
    int n = n0b + tid; n = n < NTOK ? n : NTOK - 1;
    rbN[tid] = (n / 14) * 16 * IMG + (n % 14) * 16;
  } else if (tid < 64) {
    int m = m0b + (tid - 32); m = m < NTOK ? m : NTOK - 1;
    rbM[tid - 32] = (m / 14) * 16 * IMG + (m % 14) * 16;
  }
  __syncthreads();

  const float* xb = x + (size_t)b * 3 * IMG2;
  int srow = tid >> 3;              // staging row 0..31
  int sfo  = (tid & 7) * 8;         // staging feature offset 0..56
  int rN = rbN[srow], rM = rbM[srow];
  int lane = tid & 63;
  int wid  = tid >> 6;
  int wi = wid >> 1, wj = wid & 1;
  int aq = lane >> 4;
  const double* Ap = &As[0][0];
  const double* Bp = &Bs[0][0];
  int abase = (wi * 16 + (lane & 15)) * LDP + aq;
  int bbase = (wj * 16 + (lane & 15)) * LDP + aq;

#define LOADT(d0,d1,d2,d3,kc) { int f0 = (kc) + sfo;                         \
    int c_ = f0 >> 8, h_ = (f0 >> 4) & 15, w_ = f0 & 15;                     \
    const float* p_ = xb + c_ * IMG2 + h_ * IMG + w_;                        \
    d0 = *(const float4*)(p_ + rN); d1 = *(const float4*)(p_ + rN + 4);      \
    d2 = *(const float4*)(p_ + rM); d3 = *(const float4*)(p_ + rM + 4); }

  f64x4 acc = {0.0, 0.0, 0.0, 0.0};
  f64x4 acc0 = {0.0, 0.0, 0.0, 0.0};
  float4 ca0, ca1, cb0, cb1;
  LOADT(ca0, ca1, cb0, cb1, 0)

#pragma unroll
  for (int tt = 0; tt < 12; ++tt) {
    __syncthreads();                // previous MFMA phase done reading LDS
    As[srow][sfo + 0] = (double)ca0.x; As[srow][sfo + 1] = (double)ca0.y;
    As[srow][sfo + 2] = (double)ca0.z; As[srow][sfo + 3] = (double)ca0.w;
    As[srow][sfo + 4] = (double)ca1.x; As[srow][sfo + 5] = (double)ca1.y;
    As[srow][sfo + 6] = (double)ca1.z; As[srow][sfo + 7] = (double)ca1.w;
    Bs[srow][sfo + 0] = (double)cb0.x; Bs[srow][sfo + 1] = (double)cb0.y;
    Bs[srow][sfo + 2] = (double)cb0.z; Bs[srow][sfo + 3] = (double)cb0.w;
    Bs[srow][sfo + 4] = (double)cb1.x; Bs[srow][sfo + 5] = (double)cb1.y;
    Bs[srow][sfo + 6] = (double)cb1.z; Bs[srow][sfo + 7] = (double)cb1.w;
    __syncthreads();                // tile staged
    float4 na0, na1, nb0, nb1;
    if (tt < 11) LOADT(na0, na1, nb0, nb1, (tt + 1) * KB)  // overlap with MFMA
#pragma unroll
    for (int k = 0; k < KB; k += 4)
      acc = __builtin_amdgcn_mfma_f64_16x16x4f64(Ap[abase + k], Bp[bbase + k], acc, 0, 0, 0);
    if (tt == 0) {
      if (wid == 0) {               // layout probe, tile 0 only, wave-parallel
        double q0 = As[0][lane] * Bs[0][lane];
        double q1 = As[1][lane] * Bs[0][lane];
        double q2 = As[4][lane] * Bs[0][lane];
#pragma unroll
        for (int off = 32; off; off >>= 1) {
          q0 += __shfl_down(q0, off);
          q1 += __shfl_down(q1, off);
          q2 += __shfl_down(q2, off);
        }
        if (lane == 0) { prsh[0] = q0; prsh[1] = q1; prsh[2] = q2; }
      }
      acc0 = acc;
    }
    ca0 = na0; ca1 = na1; cb0 = nb0; cb1 = nb1;
  }
#undef LOADT

  if (tid == 0) {
    double tol = 1e-9 * (1.0 + fabs(prsh[0]));
    int ok0  = fabs(prsh[0] - acc0[0]) <= tol;
    int okP1 = ok0 && (fabs(prsh[1] - acc0[1]) <= tol);
    int okP2 = ok0 && (fabs(prsh[2] - acc0[1]) <= tol);
    okf = okP1 ? 1 : (okP2 ? 2 : 0);
  }
  __syncthreads();                  // okf visible; all MFMA reads of As/Bs done
  int mode = okf;

  double (*Dt)[33] = (double(*)[33])(&As[0][0]);

  if (mode) {
#pragma unroll
    for (int i = 0; i < 4; ++i) {
      int lr = (mode == 1) ? (aq * 4 + i) : (aq + 4 * i);
      Dt[wi * 16 + lr][wj * 16 + (lane & 15)] = acc[i];
    }
  } else {
    // safety fallback: scalar f64 recompute (round-3-proven)
    double s00 = 0, s01 = 0, s10 = 0, s11 = 0;
    int ty2 = tid >> 4, tx2 = tid & 15;
    for (int kc = 0; kc < 768; kc += KB) {
      int f0 = kc + sfo;
      int c_ = f0 >> 8, h_ = (f0 >> 4) & 15, w_ = f0 & 15;
      const float* p_ = xb + c_ * IMG2 + h_ * IMG + w_;
      float4 la0 = *(const float4*)(p_ + rN), la1 = *(const float4*)(p_ + rN + 4);
      float4 lb0 = *(const float4*)(p_ + rM), lb1 = *(const float4*)(p_ + rM + 4);
      __syncthreads();
      As[srow][sfo + 0] = (double)la0.x; As[srow][sfo + 1] = (double)la0.y;
      As[srow][sfo + 2] = (double)la0.z; As[srow][sfo + 3] = (double)la0.w;
      As[srow][sfo + 4] = (double)la1.x; As[srow][sfo + 5] = (double)la1.y;
      As[srow][sfo + 6] = (double)la1.z; As[srow][sfo + 7] = (double)la1.w;
      Bs[srow][sfo + 0] = (double)lb0.x; Bs[srow][sfo + 1] = (double)lb0.y;
      Bs[srow][sfo + 2] = (double)lb0.z; Bs[srow][sfo + 3] = (double)lb0.w;
      Bs[srow][sfo + 4] = (double)lb1.x; Bs[srow][sfo + 5] = (double)lb1.y;
      Bs[srow][sfo + 6] = (double)lb1.z; Bs[srow][sfo + 7] = (double)lb1.w;
      __syncthreads();
      for (int j = 0; j < KB; ++j) {
        double a0 = As[ty2][j], a1 = As[ty2 + 16][j];
        double b0 = Bs[tx2][j], b1 = Bs[tx2 + 16][j];
        s00 += a0 * b0; s01 += a0 * b1; s10 += a1 * b0; s11 += a1 * b1;
      }
    }
    __syncthreads();
    Dt[ty2][tx2] = s00;       Dt[ty2][tx2 + 16] = s01;
    Dt[ty2 + 16][tx2] = s10;  Dt[ty2 + 16][tx2 + 16] = s11;
  }
  __syncthreads();

  // Phase B: dot -> dist, per-batch max, coalesced writes (+ mirror)
  const double* sqb = sq + b * NTOK;
  const double SQ768 = sqrt(768.0);
  int lr2 = tid >> 3, lc0 = (tid & 7) * 4;
  double dv[4];
  double lmax = 0.0;
#pragma unroll
  for (int j = 0; j < 4; ++j) {
    int n = n0b + lr2, m = m0b + lc0 + j;
    int nn = n < NTOK ? n : NTOK - 1, mm = m < NTOK ? m : NTOK - 1;
    double d2 = sqb[nn] + sqb[mm] - 2.0 * Dt[lr2][lc0 + j];
    double d = sqrt(d2 > 0.0 ? d2 : 0.0) / SQ768;
    dv[j] = d;
    Dt[lr2][lc0 + j] = d;           // keep dist in tile for mirror reads
    lmax = lmax > d ? lmax : d;
  }
  double* red = (double*)(&Bs[0][0]);
  red[tid] = lmax;
  __syncthreads();
  for (int st = 128; st; st >>= 1) {
    if (tid < st) { double o = red[tid + st]; if (o > red[tid]) red[tid] = o; }
    __syncthreads();
  }
  if (tid == 0) atomicMax(&dmax[b], (unsigned long long)__double_as_longlong(red[0]));

  double* Db = dist + (size_t)b * NTOK * NTOK;
  {
    int n = n0b + lr2, m0 = m0b + lc0;
    if (n < NTOK && m0 < NTOK) {
      if (m0 + 3 < NTOK) {
        f64x4 v = {dv[0], dv[1], dv[2], dv[3]};
        *(f64x4*)(Db + (size_t)n * NTOK + m0) = v;
      } else {
#pragma unroll
        for (int j = 0; j < 4; ++j)
          if (m0 + j < NTOK) Db[(size_t)n * NTOK + m0 + j] = dv[j];
      }
    }
  }
  if (ti != tj) {                   // mirror: D[m][n] = D[n][m]
    int m = m0b + lr2, n0 = n0b + lc0;
    if (m < NTOK && n0 < NTOK) {
      if (n0 + 3 < NTOK) {
        f64x4 v = {Dt[lc0][lr2], Dt[lc0 + 1][lr2], Dt[lc0 + 2][lr2], Dt[lc0 + 3][lr2]};
        *(f64x4*)(Db + (size_t)m * NTOK + n0) = v;
      } else {
#pragma unroll
        for (int j = 0; j < 4; ++j)
          if (n0 + j < NTOK) Db[(size_t)m * NTOK + n0 + j] = Dt[lc0 + j][lr2];
      }
    }
  }
}

// ---------------- K2: per-batch clustering, wave-parallel P1/P2/P3 ----------------
__global__ void __launch_bounds__(256) k_cluster(const double* __restrict__ dist,
    const unsigned long long* __restrict__ dmax, int* __restrict__ out,
    uint32_t kd0, uint32_t kd1, uint32_t kn0, uint32_t kn1, int B) {
  int b = blockIdx.x;
  int tid = threadIdx.x;
  int lane = tid & 63, wid = tid >> 6;
  const double* Db = dist + (size_t)b * NTOK * NTOK;
  __shared__ double dens[NTOK];
  __shared__ double score[NTOK];
  __shared__ int center[KCL];
  __shared__ short center_of[NTOK];
  __shared__ unsigned long long bkey[KCL];
  double dmaxv = __longlong_as_double((long long)dmax[b]);

  // P1: kNN(5) density; each wave owns rows wid, wid+4, ... (coalesced scans)
  for (int rr = 0; rr < 49; ++rr) {
    int n = rr * 4 + wid;
    const double* row = Db + (size_t)n * NTOK;
    double vv[4];
    vv[0] = row[lane]; vv[1] = row[lane + 64]; vv[2] = row[lane + 128];
    vv[3] = (lane + 192 < NTOK) ? row[lane + 192] : 1e300;
    unsigned taken = 0;
    double nb[5];
#pragma unroll
    for (int p = 0; p < 5; ++p) {
      double mv = 1e300; int mi = 1 << 30;
#pragma unroll
      for (int q = 0; q < 4; ++q) {
        if (!((taken >> q) & 1) && vv[q] < mv) { mv = vv[q]; mi = (q << 6) | lane; }
      }
#pragma unroll
      for (int off = 32; off; off >>= 1) {
        double ov = __shfl_down(mv, off); int oi = __shfl_down(mi, off);
        if (ov < mv || (ov == mv && oi < mi)) { mv = ov; mi = oi; }
      }
      mv = __shfl(mv, 0); mi = __shfl(mi, 0);
      nb[p] = mv;
      if (mi < (1 << 30) && (mi & 63) == lane) taken |= 1u << (mi >> 6);
    }
    if (lane == 0) {
      double acc = nb[0] * nb[0];
      acc += nb[1] * nb[1]; acc += nb[2] * nb[2];
      acc += nb[3] * nb[3]; acc += nb[4] * nb[4];
      double d = exp(-(acc / 5.0));
      double u = (double)jax_uniform(kd0, kd1, (uint32_t)(b * NTOK + n));
      dens[n] = d + u * 1e-6;
    }
  }
  __syncthreads();

  // P2: dmin over strictly-higher-density tokens (filler = dist_max), score
  for (int rr = 0; rr < 49; ++rr) {
    int n = rr * 4 + wid;
    const double* row = Db + (size_t)n * NTOK;
    double dn = dens[n];
    double v = dmaxv;
    for (int m = lane; m < NTOK; m += 64)
      if (dens[m] > dn) { double r = row[m]; v = r < v ? r : v; }
#pragma unroll
    for (int off = 32; off; off >>= 1) {
      double ov = __shfl_down(v, off);
      v = ov < v ? ov : v;
    }
    if (lane == 0) score[n] = v * dn;
  }
  __syncthreads();

  // P3: top-49 (ties -> lower index) on wave 0 only
  if (wid == 0) {
    for (int k = 0; k < KCL; ++k) {
      double mv = -1e300; int mi = 1 << 30;
#pragma unroll
      for (int q = 0; q < 4; ++q) {
        int idx = (q << 6) | lane;
        if (idx < NTOK) {
          double sv = score[idx];
          if (sv > mv || (sv == mv && idx < mi)) { mv = sv; mi = idx; }
        }
      }
#pragma unroll
      for (int off = 32; off; off >>= 1) {
        double ov = __shfl_down(mv, off); int oi = __shfl_down(mi, off);
        if (ov > mv || (ov == mv && oi < mi)) { mv = ov; mi = oi; }
      }
      mi = __shfl(mi, 0);
      if (lane == 0) { center[k] = mi; score[mi] = -1e300; }
    }
  }
  __syncthreads();

  // P4: assign to nearest center (ties -> lower k), centers self-assign
  if (tid < NTOK) center_of[tid] = -1;
  __syncthreads();
  if (tid < KCL) { center_of[center[tid]] = (short)tid; bkey[tid] = 0ULL; }
  __syncthreads();
  int mycl = 0;
  if (tid < NTOK) {
    double best = 1e300; int bk = 0;
    for (int k = 0; k < KCL; ++k) {
      double d = Db[(size_t)center[k] * NTOK + tid];
      if (d < best) { best = d; bk = k; }
    }
    short co = center_of[tid];
    if (co >= 0) bk = co;
    mycl = bk;
  }
  __syncthreads();

  // P5: representative = per-cluster max of f32 key (k+u), ties -> larger token index
  if (tid < NTOK) {
    float u = jax_uniform(kn0, kn1, (uint32_t)(b * NTOK + tid));
    float keyf = (float)mycl + u;
    unsigned long long key =
        ((unsigned long long)__float_as_uint(keyf) << 8) | (unsigned)tid;
    atomicMax(&bkey[mycl], key);
  }
  __syncthreads();
  if (tid < KCL) out[b * KCL + tid] = (int)(bkey[tid] & 0xFFu);
}

// ---------------- launch ----------------
extern "C" void kernel_launch(void* const* d_in, const int* in_sizes, int n_in,
                              void* d_out, int out_size, void* d_ws, size_t ws_size,
                              hipStream_t stream) {
  const float* x = (const float*)d_in[0];
  int B = in_sizes[0] / (3 * IMG2);           // 256
  double* dist = (double*)d_ws;
  size_t distBytes = (size_t)B * NTOK * NTOK * sizeof(double);
  double* sq = (double*)((char*)d_ws + distBytes);
  unsigned long long* dmax =
      (unsigned long long*)((char*)sq + (size_t)B * NTOK * sizeof(double));
  int* out = (int*)d_out;

  uint32_t kd0, kd1, kn0, kn1;
  tf2x32(0u, 1u, 0u, 0u, &kd0, &kd1);
  tf2x32(0u, 1u, 0u, 1u, &kn0, &kn1);

  hipMemsetAsync(dmax, 0, B * sizeof(unsigned long long), stream);
  int totalTok = B * NTOK;
  k_sq<<<dim3((totalTok + 3) / 4), dim3(256), 0, stream>>>(x, sq, B);
  k_dist_mfma<<<dim3(8 * 32 * 28), dim3(256), 0, stream>>>(x, sq, dist, dmax);
  k_cluster<<<dim3(B), dim3(256), 0, stream>>>(dist, dmax, out, kd0, kd1, kn0, kn1, B);
}

// Round 7
// 406.578 us; speedup vs baseline: 2.3475x; 1.5789x over previous
//
#include <hip/hip_runtime.h>
#include <stdint.h>

#define NTOK 196
#define KCL 49
#define IMG 224
#define IMG2 (224*224)
#define KB 64
#define LDP 68   // f32 cols + pad: b32 frag reads 2-way only (free), b128-write aligned

typedef double f64x4 __attribute__((ext_vector_type(4)));

// ---------------- JAX threefry2x32 (20 rounds), host+device ----------------
__host__ __device__ __forceinline__ void tf2x32(uint32_t k0, uint32_t k1,
    uint32_t x0, uint32_t x1, uint32_t* o0, uint32_t* o1) {
  uint32_t ks2 = k0 ^ k1 ^ 0x1BD11BDAu;
#define TFR(r) { x0 += x1; x1 = (x1 << r) | (x1 >> (32 - r)); x1 ^= x0; }
  x0 += k0; x1 += k1;
  TFR(13) TFR(15) TFR(26) TFR(6)
  x0 += k1; x1 += ks2 + 1u;
  TFR(17) TFR(29) TFR(16) TFR(24)
  x0 += ks2; x1 += k0 + 2u;
  TFR(13) TFR(15) TFR(26) TFR(6)
  x0 += k0; x1 += k1 + 3u;
  TFR(17) TFR(29) TFR(16) TFR(24)
  x0 += k1; x1 += ks2 + 4u;
  TFR(13) TFR(15) TFR(26) TFR(6)
  x0 += ks2; x1 += k0 + 5u;
#undef TFR
  *o0 = x0; *o1 = x1;
}

// jax.random.uniform f32 bits, PARTITIONABLE threefry (jax >= 0.5 default)
__device__ __forceinline__ float jax_uniform(uint32_t k0, uint32_t k1, uint32_t j) {
  uint32_t o0, o1;
  tf2x32(k0, k1, 0u, j, &o0, &o1);
  uint32_t bits = o0 ^ o1;
  return __uint_as_float((bits >> 9) | 0x3f800000u) - 1.0f;
}

// ---------------- K0: per-token sum of squares (fp64) ----------------
__global__ void __launch_bounds__(256) k_sq(const float* __restrict__ x,
                                            double* __restrict__ sq, int B) {
  int wave = blockIdx.x * 4 + (threadIdx.x >> 6);
  int lane = threadIdx.x & 63;
  if (wave >= B * NTOK) return;
  int b = wave / NTOK, n = wave % NTOK;
  int p1 = n / 14, p2 = n % 14;
  const float* xb = x + (size_t)b * 3 * IMG2;
  int rowbase = (p1 * 16) * IMG + p2 * 16;
  double acc = 0.0;
#pragma unroll
  for (int q = 0; q < 12; ++q) {
    int f = lane + q * 64;
    int c = f >> 8, h = (f >> 4) & 15, w = f & 15;
    float v = xb[c * IMG2 + rowbase + h * IMG + w];
    acc += (double)v * (double)v;
  }
#pragma unroll
  for (int off = 32; off; off >>= 1) acc += __shfl_down(acc, off);
  if (lane == 0) sq[wave] = acc;
}

// ---------------- K1: f64-MFMA Gram, f32 LDS staging, triangle+mirror -------------
// grid: 8 xcd * 32 batch-groups * 28 triangle-tiles = 7168 blocks of 256
__global__ void __launch_bounds__(256) k_dist_mfma(const float* __restrict__ x,
    const double* __restrict__ sq, double* __restrict__ dist,
    unsigned long long* __restrict__ dmax) {
  int bid = blockIdx.x;
  int xcd = bid & 7;
  int s = bid >> 3;                 // 0..895
  int b = xcd + 8 * (s / 28);
  int t = s % 28;
  int ti = 0, rem = t, rl = 7;
  while (rem >= rl) { rem -= rl; rl--; ti++; }
  int tj = ti + rem;                // ti <= tj
  int n0b = ti * 32, m0b = tj * 32;
  int tid = threadIdx.x;

  __shared__ __align__(16) float As[32][LDP];
  __shared__ __align__(16) float Bs[32][LDP];
  __shared__ int rbN[32], rbM[32];
  __shared__ double prsh[3];
  __shared__ int okf;

  if (tid < 32) {
    int n = n0b + tid; n = n < NTOK ? n : NTOK - 1;
    rbN[tid] = (n / 14) * 16 * IMG + (n % 14) * 16;
  } else if (tid < 64) {
    int m = m0b + (tid - 32); m = m < NTOK ? m : NTOK - 1;
    rbM[tid - 32] = (m / 14) * 16 * IMG + (m % 14) * 16;
  }
  __syncthreads();

  const float* xb = x + (size_t)b * 3 * IMG2;
  int srow = tid >> 3;              // staging row 0..31
  int sfo  = (tid & 7) * 8;         // staging feature offset 0..56
  int rN = rbN[srow], rM = rbM[srow];
  int lane = tid & 63;
  int wid  = tid >> 6;
  int wi = wid >> 1, wj = wid & 1;
  int aq = lane >> 4;
  const float* Ap = &As[0][0];
  const float* Bp = &Bs[0][0];
  int abase = (wi * 16 + (lane & 15)) * LDP + aq;
  int bbase = (wj * 16 + (lane & 15)) * LDP + aq;

#define LOADT(d0,d1,d2,d3,kc) { int f0 = (kc) + sfo;                         \
    int c_ = f0 >> 8, h_ = (f0 >> 4) & 15, w_ = f0 & 15;                     \
    const float* p_ = xb + c_ * IMG2 + h_ * IMG + w_;                        \
    d0 = *(const float4*)(p_ + rN); d1 = *(const float4*)(p_ + rN + 4);      \
    d2 = *(const float4*)(p_ + rM); d3 = *(const float4*)(p_ + rM + 4); }

  f64x4 acc = {0.0, 0.0, 0.0, 0.0};
  f64x4 acc0 = {0.0, 0.0, 0.0, 0.0};
  float4 ca0, ca1, cb0, cb1;
  LOADT(ca0, ca1, cb0, cb1, 0)

#pragma unroll
  for (int tt = 0; tt < 12; ++tt) {
    __syncthreads();                // previous MFMA phase done reading LDS
    *(float4*)&As[srow][sfo]     = ca0;
    *(float4*)&As[srow][sfo + 4] = ca1;
    *(float4*)&Bs[srow][sfo]     = cb0;
    *(float4*)&Bs[srow][sfo + 4] = cb1;
    __syncthreads();                // tile staged
    float4 na0, na1, nb0, nb1;
    if (tt < 11) LOADT(na0, na1, nb0, nb1, (tt + 1) * KB)  // overlap with MFMA
#pragma unroll
    for (int k = 0; k < KB; k += 4) {
      double av = (double)Ap[abase + k];
      double bv = (double)Bp[bbase + k];
      acc = __builtin_amdgcn_mfma_f64_16x16x4f64(av, bv, acc, 0, 0, 0);
    }
    if (tt == 0) {
      if (wid == 0) {               // layout probe, tile 0 only, wave-parallel
        double q0 = (double)As[0][lane] * (double)Bs[0][lane];
        double q1 = (double)As[1][lane] * (double)Bs[0][lane];
        double q2 = (double)As[4][lane] * (double)Bs[0][lane];
#pragma unroll
        for (int off = 32; off; off >>= 1) {
          q0 += __shfl_down(q0, off);
          q1 += __shfl_down(q1, off);
          q2 += __shfl_down(q2, off);
        }
        if (lane == 0) { prsh[0] = q0; prsh[1] = q1; prsh[2] = q2; }
      }
      acc0 = acc;
    }
    ca0 = na0; ca1 = na1; cb0 = nb0; cb1 = nb1;
  }
#undef LOADT

  if (tid == 0) {
    double tol = 1e-9 * (1.0 + fabs(prsh[0]));
    int ok0  = fabs(prsh[0] - acc0[0]) <= tol;
    int okP1 = ok0 && (fabs(prsh[1] - acc0[1]) <= tol);
    int okP2 = ok0 && (fabs(prsh[2] - acc0[1]) <= tol);
    okf = okP1 ? 1 : (okP2 ? 2 : 0);
  }
  __syncthreads();                  // okf visible; all MFMA reads of As/Bs done
  int mode = okf;

  double (*Dt)[33] = (double(*)[33])(&As[0][0]);  // f64 tile aliases As (8448B <= 8704B)

  if (mode) {
#pragma unroll
    for (int i = 0; i < 4; ++i) {
      int lr = (mode == 1) ? (aq * 4 + i) : (aq + 4 * i);
      Dt[wi * 16 + lr][wj * 16 + (lane & 15)] = acc[i];
    }
  } else {
    // safety fallback: scalar f64 recompute from f32 LDS staging
    double s00 = 0, s01 = 0, s10 = 0, s11 = 0;
    int ty2 = tid >> 4, tx2 = tid & 15;
    for (int kc = 0; kc < 768; kc += KB) {
      int f0 = kc + sfo;
      int c_ = f0 >> 8, h_ = (f0 >> 4) & 15, w_ = f0 & 15;
      const float* p_ = xb + c_ * IMG2 + h_ * IMG + w_;
      float4 la0 = *(const float4*)(p_ + rN), la1 = *(const float4*)(p_ + rN + 4);
      float4 lb0 = *(const float4*)(p_ + rM), lb1 = *(const float4*)(p_ + rM + 4);
      __syncthreads();
      *(float4*)&As[srow][sfo]     = la0;
      *(float4*)&As[srow][sfo + 4] = la1;
      *(float4*)&Bs[srow][sfo]     = lb0;
      *(float4*)&Bs[srow][sfo + 4] = lb1;
      __syncthreads();
      for (int j = 0; j < KB; ++j) {
        double a0 = (double)As[ty2][j], a1 = (double)As[ty2 + 16][j];
        double b0 = (double)Bs[tx2][j], b1 = (double)Bs[tx2 + 16][j];
        s00 += a0 * b0; s01 += a0 * b1; s10 += a1 * b0; s11 += a1 * b1;
      }
    }
    __syncthreads();
    Dt[ty2][tx2] = s00;       Dt[ty2][tx2 + 16] = s01;
    Dt[ty2 + 16][tx2] = s10;  Dt[ty2 + 16][tx2 + 16] = s11;
  }
  __syncthreads();

  // Phase B: dot -> dist, per-batch max, coalesced writes (+ mirror)
  const double* sqb = sq + b * NTOK;
  const double SQ768 = sqrt(768.0);
  int lr2 = tid >> 3, lc0 = (tid & 7) * 4;
  double dv[4];
  double lmax = 0.0;
#pragma unroll
  for (int j = 0; j < 4; ++j) {
    int n = n0b + lr2, m = m0b + lc0 + j;
    int nn = n < NTOK ? n : NTOK - 1, mm = m < NTOK ? m : NTOK - 1;
    double d2 = sqb[nn] + sqb[mm] - 2.0 * Dt[lr2][lc0 + j];
    double d = sqrt(d2 > 0.0 ? d2 : 0.0) / SQ768;
    dv[j] = d;
    Dt[lr2][lc0 + j] = d;           // keep dist in tile for mirror reads
    lmax = lmax > d ? lmax : d;
  }
  double* red = (double*)(&Bs[0][0]);
  red[tid] = lmax;
  __syncthreads();
  for (int st = 128; st; st >>= 1) {
    if (tid < st) { double o = red[tid + st]; if (o > red[tid]) red[tid] = o; }
    __syncthreads();
  }
  if (tid == 0) atomicMax(&dmax[b], (unsigned long long)__double_as_longlong(red[0]));

  double* Db = dist + (size_t)b * NTOK * NTOK;
  {
    int n = n0b + lr2, m0 = m0b + lc0;
    if (n < NTOK && m0 < NTOK) {
      if (m0 + 3 < NTOK) {
        f64x4 v = {dv[0], dv[1], dv[2], dv[3]};
        *(f64x4*)(Db + (size_t)n * NTOK + m0) = v;
      } else {
#pragma unroll
        for (int j = 0; j < 4; ++j)
          if (m0 + j < NTOK) Db[(size_t)n * NTOK + m0 + j] = dv[j];
      }
    }
  }
  if (ti != tj) {                   // mirror: D[m][n] = D[n][m]
    int m = m0b + lr2, n0 = n0b + lc0;
    if (m < NTOK && n0 < NTOK) {
      if (n0 + 3 < NTOK) {
        f64x4 v = {Dt[lc0][lr2], Dt[lc0 + 1][lr2], Dt[lc0 + 2][lr2], Dt[lc0 + 3][lr2]};
        *(f64x4*)(Db + (size_t)m * NTOK + n0) = v;
      } else {
#pragma unroll
        for (int j = 0; j < 4; ++j)
          if (n0 + j < NTOK) Db[(size_t)m * NTOK + n0 + j] = Dt[lc0 + j][lr2];
      }
    }
  }
}

// ---------------- K2: per-batch clustering (round-3 serial form, fp64) ------------
__global__ void __launch_bounds__(256) k_cluster(const double* __restrict__ dist,
    const unsigned long long* __restrict__ dmax, int* __restrict__ out,
    uint32_t kd0, uint32_t kd1, uint32_t kn0, uint32_t kn1, int B) {
  int b = blockIdx.x;
  int tid = threadIdx.x;
  const double* Db = dist + (size_t)b * NTOK * NTOK;
  __shared__ double dens[NTOK];
  __shared__ double score[NTOK];
  __shared__ int center[KCL];
  __shared__ short center_of[NTOK];
  __shared__ double rv[256];
  __shared__ int ri[256];
  __shared__ unsigned long long bkey[KCL];
  double dmaxv = __longlong_as_double((long long)dmax[b]);

  // P1: kNN(5) density (fp64) + threefry noise*1e-6
  if (tid < NTOK) {
    const double* row = Db + tid * NTOK;
    double nb0 = 1e300, nb1 = 1e300, nb2 = 1e300, nb3 = 1e300, nb4 = 1e300;
    for (int m = 0; m < NTOK; ++m) {
      double v = row[m];
      if (v < nb4) {
        nb4 = v;
        if (nb4 < nb3) { double t = nb3; nb3 = nb4; nb4 = t;
          if (nb3 < nb2) { t = nb2; nb2 = nb3; nb3 = t;
            if (nb2 < nb1) { t = nb1; nb1 = nb2; nb2 = t;
              if (nb1 < nb0) { t = nb0; nb0 = nb1; nb1 = t; } } } }
      }
    }
    double acc = nb0 * nb0 + nb1 * nb1 + nb2 * nb2 + nb3 * nb3 + nb4 * nb4;
    double mean = acc / 5.0;
    double d = exp(-mean);
    double u = (double)jax_uniform(kd0, kd1, (uint32_t)(b * NTOK + tid));
    dens[tid] = d + u * 1e-6;
  }
  __syncthreads();

  // P2: dmin over strictly-higher-density tokens (filler = dist_max), score
  if (tid < NTOK) {
    const double* row = Db + tid * NTOK;
    double dn = dens[tid];
    double v = dmaxv;
    for (int m = 0; m < NTOK; ++m)
      if (dens[m] > dn) { double r = row[m]; v = r < v ? r : v; }
    score[tid] = v * dens[tid];
  }
  __syncthreads();

  // P3: iterative top-49 (ties -> lower index), order = cluster id
  for (int k = 0; k < KCL; ++k) {
    double v = -1e300; int idx = 0;
    if (tid < NTOK && score[tid] >= 0.0) { v = score[tid]; idx = tid; }
    rv[tid] = v; ri[tid] = idx;
    __syncthreads();
    for (int st = 128; st; st >>= 1) {
      if (tid < st) {
        double ov = rv[tid + st]; int oi = ri[tid + st];
        if (ov > rv[tid] || (ov == rv[tid] && oi < ri[tid])) { rv[tid] = ov; ri[tid] = oi; }
      }
      __syncthreads();
    }
    if (tid == 0) {
      int n = ri[0];
      center[k] = n;
      score[n] = -1.0;  // mark taken
    }
    __syncthreads();
  }

  // P4: assign to nearest center (ties -> lower k), centers self-assign
  if (tid < NTOK) center_of[tid] = -1;
  __syncthreads();
  if (tid < KCL) { center_of[center[tid]] = (short)tid; bkey[tid] = 0ULL; }
  __syncthreads();
  int mycl = 0;
  if (tid < NTOK) {
    double best = 1e300; int bk = 0;
    for (int k = 0; k < KCL; ++k) {
      double d = Db[(size_t)center[k] * NTOK + tid];
      if (d < best) { best = d; bk = k; }
    }
    short co = center_of[tid];
    if (co >= 0) bk = co;
    mycl = bk;
  }
  __syncthreads();

  // P5: representative = per-cluster max of f32 key (k+u), ties -> larger token index
  if (tid < NTOK) {
    float u = jax_uniform(kn0, kn1, (uint32_t)(b * NTOK + tid));
    float keyf = (float)mycl + u;
    unsigned long long key =
        ((unsigned long long)__float_as_uint(keyf) << 8) | (unsigned)tid;
    atomicMax(&bkey[mycl], key);
  }
  __syncthreads();
  if (tid < KCL) out[b * KCL + tid] = (int)(bkey[tid] & 0xFFu);
}

// ---------------- launch ----------------
extern "C" void kernel_launch(void* const* d_in, const int* in_sizes, int n_in,
                              void* d_out, int out_size, void* d_ws, size_t ws_size,
                              hipStream_t stream) {
  const float* x = (const float*)d_in[0];
  int B = in_sizes[0] / (3 * IMG2);           // 256
  double* dist = (double*)d_ws;
  size_t distBytes = (size_t)B * NTOK * NTOK * sizeof(double);
  double* sq = (double*)((char*)d_ws + distBytes);
  unsigned long long* dmax =
      (unsigned long long*)((char*)sq + (size_t)B * NTOK * sizeof(double));
  int* out = (int*)d_out;

  uint32_t kd0, kd1, kn0, kn1;
  tf2x32(0u, 1u, 0u, 0u, &kd0, &kd1);
  tf2x32(0u, 1u, 0u, 1u, &kn0, &kn1);

  hipMemsetAsync(dmax, 0, B * sizeof(unsigned long long), stream);
  int totalTok = B * NTOK;
  k_sq<<<dim3((totalTok + 3) / 4), dim3(256), 0, stream>>>(x, sq, B);
  k_dist_mfma<<<dim3(8 * 32 * 28), dim3(256), 0, stream>>>(x, sq, dist, dmax);
  k_cluster<<<dim3(B), dim3(256), 0, stream>>>(dist, dmax, out, kd0, kd1, kn0, kn1, B);
}

// Round 8
// 364.239 us; speedup vs baseline: 2.6204x; 1.1162x over previous
//
#include <hip/hip_runtime.h>
#include <stdint.h>

#define NTOK 196
#define KCL 49
#define IMG 224
#define IMG2 (224*224)
#define KB 64
#define LDP 68   // f32 cols + pad: b32 frag reads 2-way only (free), b128-write aligned

typedef double f64x4 __attribute__((ext_vector_type(4)));

// ---------------- JAX threefry2x32 (20 rounds), host+device ----------------
__host__ __device__ __forceinline__ void tf2x32(uint32_t k0, uint32_t k1,
    uint32_t x0, uint32_t x1, uint32_t* o0, uint32_t* o1) {
  uint32_t ks2 = k0 ^ k1 ^ 0x1BD11BDAu;
#define TFR(r) { x0 += x1; x1 = (x1 << r) | (x1 >> (32 - r)); x1 ^= x0; }
  x0 += k0; x1 += k1;
  TFR(13) TFR(15) TFR(26) TFR(6)
  x0 += k1; x1 += ks2 + 1u;
  TFR(17) TFR(29) TFR(16) TFR(24)
  x0 += ks2; x1 += k0 + 2u;
  TFR(13) TFR(15) TFR(26) TFR(6)
  x0 += k0; x1 += k1 + 3u;
  TFR(17) TFR(29) TFR(16) TFR(24)
  x0 += k1; x1 += ks2 + 4u;
  TFR(13) TFR(15) TFR(26) TFR(6)
  x0 += ks2; x1 += k0 + 5u;
#undef TFR
  *o0 = x0; *o1 = x1;
}

// jax.random.uniform f32 bits, PARTITIONABLE threefry (jax >= 0.5 default)
__device__ __forceinline__ float jax_uniform(uint32_t k0, uint32_t k1, uint32_t j) {
  uint32_t o0, o1;
  tf2x32(k0, k1, 0u, j, &o0, &o1);
  uint32_t bits = o0 ^ o1;
  return __uint_as_float((bits >> 9) | 0x3f800000u) - 1.0f;
}

// ---------------- K0: per-token sum of squares (fp64) ----------------
__global__ void __launch_bounds__(256) k_sq(const float* __restrict__ x,
                                            double* __restrict__ sq, int B) {
  int wave = blockIdx.x * 4 + (threadIdx.x >> 6);
  int lane = threadIdx.x & 63;
  if (wave >= B * NTOK) return;
  int b = wave / NTOK, n = wave % NTOK;
  int p1 = n / 14, p2 = n % 14;
  const float* xb = x + (size_t)b * 3 * IMG2;
  int rowbase = (p1 * 16) * IMG + p2 * 16;
  double acc = 0.0;
#pragma unroll
  for (int q = 0; q < 12; ++q) {
    int f = lane + q * 64;
    int c = f >> 8, h = (f >> 4) & 15, w = f & 15;
    float v = xb[c * IMG2 + rowbase + h * IMG + w];
    acc += (double)v * (double)v;
  }
#pragma unroll
  for (int off = 32; off; off >>= 1) acc += __shfl_down(acc, off);
  if (lane == 0) sq[wave] = acc;
}

// ---------------- K1: f64-MFMA Gram, f32 LDS staging, triangle+mirror -------------
// grid: 8 xcd * 32 batch-groups * 28 triangle-tiles = 7168 blocks of 256
__global__ void __launch_bounds__(256) k_dist_mfma(const float* __restrict__ x,
    const double* __restrict__ sq, double* __restrict__ dist,
    unsigned long long* __restrict__ dmax) {
  int bid = blockIdx.x;
  int xcd = bid & 7;
  int s = bid >> 3;                 // 0..895
  int b = xcd + 8 * (s / 28);
  int t = s % 28;
  int ti = 0, rem = t, rl = 7;
  while (rem >= rl) { rem -= rl; rl--; ti++; }
  int tj = ti + rem;                // ti <= tj
  int n0b = ti * 32, m0b = tj * 32;
  int tid = threadIdx.x;

  __shared__ __align__(16) float As[32][LDP];
  __shared__ __align__(16) float Bs[32][LDP];
  __shared__ int rbN[32], rbM[32];
  __shared__ double prsh[3];
  __shared__ int okf;

  if (tid < 32) {
    int n = n0b + tid; n = n < NTOK ? n : NTOK - 1;
    rbN[tid] = (n / 14) * 16 * IMG + (n % 14) * 16;
  } else if (tid < 64) {
    int m = m0b + (tid - 32); m = m < NTOK ? m : NTOK - 1;
    rbM[tid - 32] = (m / 14) * 16 * IMG + (m % 14) * 16;
  }
  __syncthreads();

  const float* xb = x + (size_t)b * 3 * IMG2;
  int srow = tid >> 3;              // staging row 0..31
  int sfo  = (tid & 7) * 8;         // staging feature offset 0..56
  int rN = rbN[srow], rM = rbM[srow];
  int lane = tid & 63;
  int wid  = tid >> 6;
  int wi = wid >> 1, wj = wid & 1;
  int aq = lane >> 4;
  const float* Ap = &As[0][0];
  const float* Bp = &Bs[0][0];
  int abase = (wi * 16 + (lane & 15)) * LDP + aq;
  int bbase = (wj * 16 + (lane & 15)) * LDP + aq;

#define LOADT(d0,d1,d2,d3,kc) { int f0 = (kc) + sfo;                         \
    int c_ = f0 >> 8, h_ = (f0 >> 4) & 15, w_ = f0 & 15;                     \
    const float* p_ = xb + c_ * IMG2 + h_ * IMG + w_;                        \
    d0 = *(const float4*)(p_ + rN); d1 = *(const float4*)(p_ + rN + 4);      \
    d2 = *(const float4*)(p_ + rM); d3 = *(const float4*)(p_ + rM + 4); }

  f64x4 acc = {0.0, 0.0, 0.0, 0.0};
  f64x4 acc0 = {0.0, 0.0, 0.0, 0.0};
  float4 ca0, ca1, cb0, cb1;
  LOADT(ca0, ca1, cb0, cb1, 0)

#pragma unroll
  for (int tt = 0; tt < 12; ++tt) {
    __syncthreads();                // previous MFMA phase done reading LDS
    *(float4*)&As[srow][sfo]     = ca0;
    *(float4*)&As[srow][sfo + 4] = ca1;
    *(float4*)&Bs[srow][sfo]     = cb0;
    *(float4*)&Bs[srow][sfo + 4] = cb1;
    __syncthreads();                // tile staged
    float4 na0, na1, nb0, nb1;
    if (tt < 11) LOADT(na0, na1, nb0, nb1, (tt + 1) * KB)  // overlap with MFMA
#pragma unroll
    for (int k = 0; k < KB; k += 4) {
      double av = (double)Ap[abase + k];
      double bv = (double)Bp[bbase + k];
      acc = __builtin_amdgcn_mfma_f64_16x16x4f64(av, bv, acc, 0, 0, 0);
    }
    if (tt == 0) {
      if (wid == 0) {               // layout probe, tile 0 only, wave-parallel
        double q0 = (double)As[0][lane] * (double)Bs[0][lane];
        double q1 = (double)As[1][lane] * (double)Bs[0][lane];
        double q2 = (double)As[4][lane] * (double)Bs[0][lane];
#pragma unroll
        for (int off = 32; off; off >>= 1) {
          q0 += __shfl_down(q0, off);
          q1 += __shfl_down(q1, off);
          q2 += __shfl_down(q2, off);
        }
        if (lane == 0) { prsh[0] = q0; prsh[1] = q1; prsh[2] = q2; }
      }
      acc0 = acc;
    }
    ca0 = na0; ca1 = na1; cb0 = nb0; cb1 = nb1;
  }
#undef LOADT

  if (tid == 0) {
    double tol = 1e-9 * (1.0 + fabs(prsh[0]));
    int ok0  = fabs(prsh[0] - acc0[0]) <= tol;
    int okP1 = ok0 && (fabs(prsh[1] - acc0[1]) <= tol);
    int okP2 = ok0 && (fabs(prsh[2] - acc0[1]) <= tol);
    okf = okP1 ? 1 : (okP2 ? 2 : 0);
  }
  __syncthreads();                  // okf visible; all MFMA reads of As/Bs done
  int mode = okf;

  double (*Dt)[33] = (double(*)[33])(&As[0][0]);  // f64 tile aliases As (8448B <= 8704B)

  if (mode) {
#pragma unroll
    for (int i = 0; i < 4; ++i) {
      int lr = (mode == 1) ? (aq * 4 + i) : (aq + 4 * i);
      Dt[wi * 16 + lr][wj * 16 + (lane & 15)] = acc[i];
    }
  } else {
    // safety fallback: scalar f64 recompute from f32 LDS staging
    double s00 = 0, s01 = 0, s10 = 0, s11 = 0;
    int ty2 = tid >> 4, tx2 = tid & 15;
    for (int kc = 0; kc < 768; kc += KB) {
      int f0 = kc + sfo;
      int c_ = f0 >> 8, h_ = (f0 >> 4) & 15, w_ = f0 & 15;
      const float* p_ = xb + c_ * IMG2 + h_ * IMG + w_;
      float4 la0 = *(const float4*)(p_ + rN), la1 = *(const float4*)(p_ + rN + 4);
      float4 lb0 = *(const float4*)(p_ + rM), lb1 = *(const float4*)(p_ + rM + 4);
      __syncthreads();
      *(float4*)&As[srow][sfo]     = la0;
      *(float4*)&As[srow][sfo + 4] = la1;
      *(float4*)&Bs[srow][sfo]     = lb0;
      *(float4*)&Bs[srow][sfo + 4] = lb1;
      __syncthreads();
      for (int j = 0; j < KB; ++j) {
        double a0 = (double)As[ty2][j], a1 = (double)As[ty2 + 16][j];
        double b0 = (double)Bs[tx2][j], b1 = (double)Bs[tx2 + 16][j];
        s00 += a0 * b0; s01 += a0 * b1; s10 += a1 * b0; s11 += a1 * b1;
      }
    }
    __syncthreads();
    Dt[ty2][tx2] = s00;       Dt[ty2][tx2 + 16] = s01;
    Dt[ty2 + 16][tx2] = s10;  Dt[ty2 + 16][tx2 + 16] = s11;
  }
  __syncthreads();

  // Phase B: dot -> dist, per-batch max, coalesced writes (+ mirror)
  const double* sqb = sq + b * NTOK;
  const double SQ768 = sqrt(768.0);
  int lr2 = tid >> 3, lc0 = (tid & 7) * 4;
  double dv[4];
  double lmax = 0.0;
#pragma unroll
  for (int j = 0; j < 4; ++j) {
    int n = n0b + lr2, m = m0b + lc0 + j;
    int nn = n < NTOK ? n : NTOK - 1, mm = m < NTOK ? m : NTOK - 1;
    double d2 = sqb[nn] + sqb[mm] - 2.0 * Dt[lr2][lc0 + j];
    double d = sqrt(d2 > 0.0 ? d2 : 0.0) / SQ768;
    dv[j] = d;
    Dt[lr2][lc0 + j] = d;           // keep dist in tile for mirror reads
    lmax = lmax > d ? lmax : d;
  }
  double* red = (double*)(&Bs[0][0]);
  red[tid] = lmax;
  __syncthreads();
  for (int st = 128; st; st >>= 1) {
    if (tid < st) { double o = red[tid + st]; if (o > red[tid]) red[tid] = o; }
    __syncthreads();
  }
  if (tid == 0) atomicMax(&dmax[b], (unsigned long long)__double_as_longlong(red[0]));

  double* Db = dist + (size_t)b * NTOK * NTOK;
  {
    int n = n0b + lr2, m0 = m0b + lc0;
    if (n < NTOK && m0 < NTOK) {
      if (m0 + 3 < NTOK) {
        f64x4 v = {dv[0], dv[1], dv[2], dv[3]};
        *(f64x4*)(Db + (size_t)n * NTOK + m0) = v;
      } else {
#pragma unroll
        for (int j = 0; j < 4; ++j)
          if (m0 + j < NTOK) Db[(size_t)n * NTOK + m0 + j] = dv[j];
      }
    }
  }
  if (ti != tj) {                   // mirror: D[m][n] = D[n][m]
    int m = m0b + lr2, n0 = n0b + lc0;
    if (m < NTOK && n0 < NTOK) {
      if (n0 + 3 < NTOK) {
        f64x4 v = {Dt[lc0][lr2], Dt[lc0 + 1][lr2], Dt[lc0 + 2][lr2], Dt[lc0 + 3][lr2]};
        *(f64x4*)(Db + (size_t)m * NTOK + n0) = v;
      } else {
#pragma unroll
        for (int j = 0; j < 4; ++j)
          if (n0 + j < NTOK) Db[(size_t)m * NTOK + n0 + j] = Dt[lc0 + j][lr2];
      }
    }
  }
}

// ---------------- K2: per-batch clustering; symmetric-coalesced P1/P2 -------------
// dist is symmetric (both halves written from the same double), so
// row[tid][m] == Db[m*NTOK+tid] bit-exactly -> column-order loads are coalesced.
__global__ void __launch_bounds__(256) k_cluster(const double* __restrict__ dist,
    const unsigned long long* __restrict__ dmax, int* __restrict__ out,
    uint32_t kd0, uint32_t kd1, uint32_t kn0, uint32_t kn1, int B) {
  int b = blockIdx.x;
  int tid = threadIdx.x;
  int lane = tid & 63, wid = tid >> 6;
  const double* Db = dist + (size_t)b * NTOK * NTOK;
  __shared__ double dens[NTOK];
  __shared__ double score[NTOK];
  __shared__ int center[KCL];
  __shared__ short center_of[NTOK];
  __shared__ unsigned long long bkey[KCL];
  double dmaxv = __longlong_as_double((long long)dmax[b]);

  // P1: kNN(5) density (fp64) + threefry noise*1e-6  [coalesced via symmetry]
  if (tid < NTOK) {
    double nb0 = 1e300, nb1 = 1e300, nb2 = 1e300, nb3 = 1e300, nb4 = 1e300;
    for (int m = 0; m < NTOK; ++m) {
      double v = Db[(size_t)m * NTOK + tid];   // == dist[tid][m]
      if (v < nb4) {
        nb4 = v;
        if (nb4 < nb3) { double t = nb3; nb3 = nb4; nb4 = t;
          if (nb3 < nb2) { t = nb2; nb2 = nb3; nb3 = t;
            if (nb2 < nb1) { t = nb1; nb1 = nb2; nb2 = t;
              if (nb1 < nb0) { t = nb0; nb0 = nb1; nb1 = t; } } } }
      }
    }
    double acc = nb0 * nb0 + nb1 * nb1 + nb2 * nb2 + nb3 * nb3 + nb4 * nb4;
    double mean = acc / 5.0;
    double d = exp(-mean);
    double u = (double)jax_uniform(kd0, kd1, (uint32_t)(b * NTOK + tid));
    dens[tid] = d + u * 1e-6;
  }
  __syncthreads();

  // P2: dmin over strictly-higher-density tokens (filler = dist_max), score
  if (tid < NTOK) {
    double dn = dens[tid];
    double v = dmaxv;
    for (int m = 0; m < NTOK; ++m) {
      double r = Db[(size_t)m * NTOK + tid];   // == dist[tid][m]; unconditional (coalesced)
      if (dens[m] > dn && r < v) v = r;
    }
    score[tid] = v * dn;
  }
  __syncthreads();

  // P3: iterative top-49 (ties -> lower index) on wave 0, scores in registers
  if (wid == 0) {
    double s0 = (lane < NTOK) ? score[lane] : -1e300;
    double s1 = score[lane + 64];
    double s2 = score[lane + 128];
    double s3 = (lane + 192 < NTOK) ? score[lane + 192] : -1e300;
    for (int k = 0; k < KCL; ++k) {
      double mv = s0; int mi = lane;
      if (s1 > mv) { mv = s1; mi = lane + 64; }
      if (s2 > mv) { mv = s2; mi = lane + 128; }
      if (s3 > mv) { mv = s3; mi = lane + 192; }
#pragma unroll
      for (int off = 32; off; off >>= 1) {
        double ov = __shfl_down(mv, off); int oi = __shfl_down(mi, off);
        if (ov > mv || (ov == mv && oi < mi)) { mv = ov; mi = oi; }
      }
      mi = __shfl(mi, 0);
      if (lane == 0) center[k] = mi;
      if (mi == lane) s0 = -1e300;
      else if (mi == lane + 64) s1 = -1e300;
      else if (mi == lane + 128) s2 = -1e300;
      else if (mi == lane + 192) s3 = -1e300;
    }
  }
  __syncthreads();

  // P4: assign to nearest center (ties -> lower k), centers self-assign
  if (tid < NTOK) center_of[tid] = -1;
  __syncthreads();
  if (tid < KCL) { center_of[center[tid]] = (short)tid; bkey[tid] = 0ULL; }
  __syncthreads();
  int mycl = 0;
  if (tid < NTOK) {
    double best = 1e300; int bk = 0;
    for (int k = 0; k < KCL; ++k) {
      double d = Db[(size_t)center[k] * NTOK + tid];   // coalesced
      if (d < best) { best = d; bk = k; }
    }
    short co = center_of[tid];
    if (co >= 0) bk = co;
    mycl = bk;
  }
  __syncthreads();

  // P5: representative = per-cluster max of f32 key (k+u), ties -> larger token index
  if (tid < NTOK) {
    float u = jax_uniform(kn0, kn1, (uint32_t)(b * NTOK + tid));
    float keyf = (float)mycl + u;
    unsigned long long key =
        ((unsigned long long)__float_as_uint(keyf) << 8) | (unsigned)tid;
    atomicMax(&bkey[mycl], key);
  }
  __syncthreads();
  if (tid < KCL) out[b * KCL + tid] = (int)(bkey[tid] & 0xFFu);
}

// ---------------- launch ----------------
extern "C" void kernel_launch(void* const* d_in, const int* in_sizes, int n_in,
                              void* d_out, int out_size, void* d_ws, size_t ws_size,
                              hipStream_t stream) {
  const float* x = (const float*)d_in[0];
  int B = in_sizes[0] / (3 * IMG2);           // 256
  double* dist = (double*)d_ws;
  size_t distBytes = (size_t)B * NTOK * NTOK * sizeof(double);
  double* sq = (double*)((char*)d_ws + distBytes);
  unsigned long long* dmax =
      (unsigned long long*)((char*)sq + (size_t)B * NTOK * sizeof(double));
  int* out = (int*)d_out;

  uint32_t kd0, kd1, kn0, kn1;
  tf2x32(0u, 1u, 0u, 0u, &kd0, &kd1);
  tf2x32(0u, 1u, 0u, 1u, &kn0, &kn1);

  hipMemsetAsync(dmax, 0, B * sizeof(unsigned long long), stream);
  int totalTok = B * NTOK;
  k_sq<<<dim3((totalTok + 3) / 4), dim3(256), 0, stream>>>(x, sq, B);
  k_dist_mfma<<<dim3(8 * 32 * 28), dim3(256), 0, stream>>>(x, sq, dist, dmax);
  k_cluster<<<dim3(B), dim3(256), 0, stream>>>(dist, dmax, out, kd0, kd1, kn0, kn1, B);
}

// Round 9
// 363.236 us; speedup vs baseline: 2.6276x; 1.0028x over previous
//
#include <hip/hip_runtime.h>
#include <stdint.h>

#define NTOK 196
#define KCL 49
#define IMG 224
#define IMG2 (224*224)
#define KB 64
#define LDP 68   // f32 cols + pad: b32 frag reads 2-way only (free), b128-write aligned

typedef double f64x4 __attribute__((ext_vector_type(4)));

// ---------------- JAX threefry2x32 (20 rounds), host+device ----------------
__host__ __device__ __forceinline__ void tf2x32(uint32_t k0, uint32_t k1,
    uint32_t x0, uint32_t x1, uint32_t* o0, uint32_t* o1) {
  uint32_t ks2 = k0 ^ k1 ^ 0x1BD11BDAu;
#define TFR(r) { x0 += x1; x1 = (x1 << r) | (x1 >> (32 - r)); x1 ^= x0; }
  x0 += k0; x1 += k1;
  TFR(13) TFR(15) TFR(26) TFR(6)
  x0 += k1; x1 += ks2 + 1u;
  TFR(17) TFR(29) TFR(16) TFR(24)
  x0 += ks2; x1 += k0 + 2u;
  TFR(13) TFR(15) TFR(26) TFR(6)
  x0 += k0; x1 += k1 + 3u;
  TFR(17) TFR(29) TFR(16) TFR(24)
  x0 += k1; x1 += ks2 + 4u;
  TFR(13) TFR(15) TFR(26) TFR(6)
  x0 += ks2; x1 += k0 + 5u;
#undef TFR
  *o0 = x0; *o1 = x1;
}

// jax.random.uniform f32 bits, PARTITIONABLE threefry (jax >= 0.5 default)
__device__ __forceinline__ float jax_uniform(uint32_t k0, uint32_t k1, uint32_t j) {
  uint32_t o0, o1;
  tf2x32(k0, k1, 0u, j, &o0, &o1);
  uint32_t bits = o0 ^ o1;
  return __uint_as_float((bits >> 9) | 0x3f800000u) - 1.0f;
}

// ---------------- K1: f64-MFMA Gram, f32 LDS staging, fused sq, triangle+mirror ----
// grid: 8 xcd * 32 batch-groups * 28 triangle-tiles = 7168 blocks of 256
__global__ void __launch_bounds__(256) k_dist_mfma(const float* __restrict__ x,
    double* __restrict__ dist, unsigned long long* __restrict__ dmax) {
  int bid = blockIdx.x;
  int xcd = bid & 7;
  int s = bid >> 3;                 // 0..895
  int b = xcd + 8 * (s / 28);
  int t = s % 28;
  int ti = 0, rem = t, rl = 7;
  while (rem >= rl) { rem -= rl; rl--; ti++; }
  int tj = ti + rem;                // ti <= tj
  int n0b = ti * 32, m0b = tj * 32;
  int tid = threadIdx.x;

  __shared__ __align__(16) float As[32][LDP];
  __shared__ __align__(16) float Bs[32][LDP];
  __shared__ int rbN[32], rbM[32];
  __shared__ double prsh[3];
  __shared__ int okf;
  __shared__ double sqpA[32][8], sqpB[32][8];
  __shared__ double sqN[32], sqM[32];

  if (tid < 32) {
    int n = n0b + tid; n = n < NTOK ? n : NTOK - 1;
    rbN[tid] = (n / 14) * 16 * IMG + (n % 14) * 16;
  } else if (tid < 64) {
    int m = m0b + (tid - 32); m = m < NTOK ? m : NTOK - 1;
    rbM[tid - 32] = (m / 14) * 16 * IMG + (m % 14) * 16;
  }
  __syncthreads();

  const float* xb = x + (size_t)b * 3 * IMG2;
  int srow = tid >> 3;              // staging row 0..31
  int sfo  = (tid & 7) * 8;         // staging feature offset 0..56
  int rN = rbN[srow], rM = rbM[srow];
  int lane = tid & 63;
  int wid  = tid >> 6;
  int wi = wid >> 1, wj = wid & 1;
  int aq = lane >> 4;
  const float* Ap = &As[0][0];
  const float* Bp = &Bs[0][0];
  int abase = (wi * 16 + (lane & 15)) * LDP + aq;
  int bbase = (wj * 16 + (lane & 15)) * LDP + aq;

#define LOADT(d0,d1,d2,d3,kc) { int f0 = (kc) + sfo;                         \
    int c_ = f0 >> 8, h_ = (f0 >> 4) & 15, w_ = f0 & 15;                     \
    const float* p_ = xb + c_ * IMG2 + h_ * IMG + w_;                        \
    d0 = *(const float4*)(p_ + rN); d1 = *(const float4*)(p_ + rN + 4);      \
    d2 = *(const float4*)(p_ + rM); d3 = *(const float4*)(p_ + rM + 4); }

  f64x4 acc = {0.0, 0.0, 0.0, 0.0};
  f64x4 acc0 = {0.0, 0.0, 0.0, 0.0};
  double psqA = 0.0, psqB = 0.0;    // fused sum-of-squares partials
  float4 ca0, ca1, cb0, cb1;
  LOADT(ca0, ca1, cb0, cb1, 0)

#pragma unroll
  for (int tt = 0; tt < 12; ++tt) {
    __syncthreads();                // previous MFMA phase done reading LDS
    *(float4*)&As[srow][sfo]     = ca0;
    *(float4*)&As[srow][sfo + 4] = ca1;
    *(float4*)&Bs[srow][sfo]     = cb0;
    *(float4*)&Bs[srow][sfo + 4] = cb1;
    // accumulate sq from the registers being staged (ascending k order)
    psqA += (double)ca0.x * ca0.x; psqA += (double)ca0.y * ca0.y;
    psqA += (double)ca0.z * ca0.z; psqA += (double)ca0.w * ca0.w;
    psqA += (double)ca1.x * ca1.x; psqA += (double)ca1.y * ca1.y;
    psqA += (double)ca1.z * ca1.z; psqA += (double)ca1.w * ca1.w;
    psqB += (double)cb0.x * cb0.x; psqB += (double)cb0.y * cb0.y;
    psqB += (double)cb0.z * cb0.z; psqB += (double)cb0.w * cb0.w;
    psqB += (double)cb1.x * cb1.x; psqB += (double)cb1.y * cb1.y;
    psqB += (double)cb1.z * cb1.z; psqB += (double)cb1.w * cb1.w;
    __syncthreads();                // tile staged
    float4 na0, na1, nb0, nb1;
    if (tt < 11) LOADT(na0, na1, nb0, nb1, (tt + 1) * KB)  // overlap with MFMA
#pragma unroll
    for (int k = 0; k < KB; k += 4) {
      double av = (double)Ap[abase + k];
      double bv = (double)Bp[bbase + k];
      acc = __builtin_amdgcn_mfma_f64_16x16x4f64(av, bv, acc, 0, 0, 0);
    }
    if (tt == 0) {
      if (wid == 0) {               // layout probe, tile 0 only, wave-parallel
        double q0 = (double)As[0][lane] * (double)Bs[0][lane];
        double q1 = (double)As[1][lane] * (double)Bs[0][lane];
        double q2 = (double)As[4][lane] * (double)Bs[0][lane];
#pragma unroll
        for (int off = 32; off; off >>= 1) {
          q0 += __shfl_down(q0, off);
          q1 += __shfl_down(q1, off);
          q2 += __shfl_down(q2, off);
        }
        if (lane == 0) { prsh[0] = q0; prsh[1] = q1; prsh[2] = q2; }
      }
      acc0 = acc;
    }
    ca0 = na0; ca1 = na1; cb0 = nb0; cb1 = nb1;
  }
#undef LOADT

  sqpA[srow][tid & 7] = psqA;
  sqpB[srow][tid & 7] = psqB;
  if (tid == 0) {
    double tol = 1e-9 * (1.0 + fabs(prsh[0]));
    int ok0  = fabs(prsh[0] - acc0[0]) <= tol;
    int okP1 = ok0 && (fabs(prsh[1] - acc0[1]) <= tol);
    int okP2 = ok0 && (fabs(prsh[2] - acc0[1]) <= tol);
    okf = okP1 ? 1 : (okP2 ? 2 : 0);
  }
  __syncthreads();                  // okf + sq partials visible; MFMA reads done
  int mode = okf;

  double (*Dt)[33] = (double(*)[33])(&As[0][0]);  // f64 tile aliases As

  if (mode) {
#pragma unroll
    for (int i = 0; i < 4; ++i) {
      int lr = (mode == 1) ? (aq * 4 + i) : (aq + 4 * i);
      Dt[wi * 16 + lr][wj * 16 + (lane & 15)] = acc[i];
    }
  } else {
    // safety fallback: scalar f64 recompute from f32 LDS staging
    double s00 = 0, s01 = 0, s10 = 0, s11 = 0;
    int ty2 = tid >> 4, tx2 = tid & 15;
    for (int kc = 0; kc < 768; kc += KB) {
      int f0 = kc + sfo;
      int c_ = f0 >> 8, h_ = (f0 >> 4) & 15, w_ = f0 & 15;
      const float* p_ = xb + c_ * IMG2 + h_ * IMG + w_;
      float4 la0 = *(const float4*)(p_ + rN), la1 = *(const float4*)(p_ + rN + 4);
      float4 lb0 = *(const float4*)(p_ + rM), lb1 = *(const float4*)(p_ + rM + 4);
      __syncthreads();
      *(float4*)&As[srow][sfo]     = la0;
      *(float4*)&As[srow][sfo + 4] = la1;
      *(float4*)&Bs[srow][sfo]     = lb0;
      *(float4*)&Bs[srow][sfo + 4] = lb1;
      __syncthreads();
      for (int j = 0; j < KB; ++j) {
        double a0 = (double)As[ty2][j], a1 = (double)As[ty2 + 16][j];
        double b0 = (double)Bs[tx2][j], b1 = (double)Bs[tx2 + 16][j];
        s00 += a0 * b0; s01 += a0 * b1; s10 += a1 * b0; s11 += a1 * b1;
      }
    }
    __syncthreads();
    Dt[ty2][tx2] = s00;       Dt[ty2][tx2 + 16] = s01;
    Dt[ty2 + 16][tx2] = s10;  Dt[ty2 + 16][tx2 + 16] = s11;
  }
  // reduce sq partials (ascending j) while Dt scatter settles
  if (tid < 32) {
    double a = sqpA[tid][0];
#pragma unroll
    for (int j = 1; j < 8; ++j) a += sqpA[tid][j];
    sqN[tid] = a;
  } else if (tid < 64) {
    double a = sqpB[tid - 32][0];
#pragma unroll
    for (int j = 1; j < 8; ++j) a += sqpB[tid - 32][j];
    sqM[tid - 32] = a;
  }
  __syncthreads();

  // Phase B: dot -> dist, per-batch max, coalesced writes (+ mirror)
  const double SQ768 = sqrt(768.0);
  int lr2 = tid >> 3, lc0 = (tid & 7) * 4;
  double dv[4];
  double lmax = 0.0;
#pragma unroll
  for (int j = 0; j < 4; ++j) {
    double d2 = sqN[lr2] + sqM[lc0 + j] - 2.0 * Dt[lr2][lc0 + j];
    double d = sqrt(d2 > 0.0 ? d2 : 0.0) / SQ768;
    dv[j] = d;
    lmax = lmax > d ? lmax : d;
  }
#pragma unroll
  for (int j = 0; j < 4; ++j) Dt[lr2][lc0 + j] = dv[j];  // keep for mirror reads
  double* red = (double*)(&Bs[0][0]);
  red[tid] = lmax;
  __syncthreads();
  for (int st = 128; st; st >>= 1) {
    if (tid < st) { double o = red[tid + st]; if (o > red[tid]) red[tid] = o; }
    __syncthreads();
  }
  if (tid == 0) atomicMax(&dmax[b], (unsigned long long)__double_as_longlong(red[0]));

  double* Db = dist + (size_t)b * NTOK * NTOK;
  {
    int n = n0b + lr2, m0 = m0b + lc0;
    if (n < NTOK && m0 < NTOK) {
      if (m0 + 3 < NTOK) {
        f64x4 v = {dv[0], dv[1], dv[2], dv[3]};
        *(f64x4*)(Db + (size_t)n * NTOK + m0) = v;
      } else {
#pragma unroll
        for (int j = 0; j < 4; ++j)
          if (m0 + j < NTOK) Db[(size_t)n * NTOK + m0 + j] = dv[j];
      }
    }
  }
  if (ti != tj) {                   // mirror: D[m][n] = D[n][m]
    int m = m0b + lr2, n0 = n0b + lc0;
    if (m < NTOK && n0 < NTOK) {
      if (n0 + 3 < NTOK) {
        f64x4 v = {Dt[lc0][lr2], Dt[lc0 + 1][lr2], Dt[lc0 + 2][lr2], Dt[lc0 + 3][lr2]};
        *(f64x4*)(Db + (size_t)m * NTOK + n0) = v;
      } else {
#pragma unroll
        for (int j = 0; j < 4; ++j)
          if (n0 + j < NTOK) Db[(size_t)m * NTOK + n0 + j] = Dt[lc0 + j][lr2];
      }
    }
  }
}

// ---------------- K2: fused clustering, 512 threads, split m-scans ----------------
// thread pair (t, t+196) splits each token's m-scan in half; 8 waves/CU.
__global__ void __launch_bounds__(512) k_cluster2(const double* __restrict__ dist,
    const unsigned long long* __restrict__ dmax, int* __restrict__ out,
    uint32_t kd0, uint32_t kd1, uint32_t kn0, uint32_t kn1, int B) {
  int b = blockIdx.x;
  int tid = threadIdx.x;
  int lane = tid & 63, wid = tid >> 6;
  const double* Db = dist + (size_t)b * NTOK * NTOK;
  __shared__ double nbsh[NTOK * 5];       // P1 partial lists; reused as vhsh
  __shared__ double dens[NTOK];
  __shared__ double score[NTOK];
  __shared__ int center[KCL];
  __shared__ short center_of[NTOK];
  __shared__ unsigned long long bkey[KCL];
  double dmaxv = __longlong_as_double((long long)dmax[b]);

  int t = (tid < NTOK) ? tid : tid - NTOK;     // token
  int half = (tid < NTOK) ? 0 : 1;             // m-range half
  bool act = tid < 2 * NTOK;
  int m0 = half ? 98 : 0, m1 = half ? NTOK : 98;

  // P1: partial 5-NN over half the row (coalesced via symmetry: Db[m][t]==dist[t][m])
  double nb0 = 1e300, nb1 = 1e300, nb2 = 1e300, nb3 = 1e300, nb4 = 1e300;
  if (act) {
    for (int m = m0; m < m1; ++m) {
      double v = Db[(size_t)m * NTOK + t];
      if (v < nb4) {
        nb4 = v;
        if (nb4 < nb3) { double w = nb3; nb3 = nb4; nb4 = w;
          if (nb3 < nb2) { w = nb2; nb2 = nb3; nb3 = w;
            if (nb2 < nb1) { w = nb1; nb1 = nb2; nb2 = w;
              if (nb1 < nb0) { w = nb0; nb0 = nb1; nb1 = w; } } } }
      }
    }
    if (half) {
      nbsh[t * 5 + 0] = nb0; nbsh[t * 5 + 1] = nb1; nbsh[t * 5 + 2] = nb2;
      nbsh[t * 5 + 3] = nb3; nbsh[t * 5 + 4] = nb4;
    }
  }
  __syncthreads();
  if (tid < NTOK) {
    // merge two sorted-ascending 5-lists, summing squares of the 5 smallest in order
    double ax = nb0, a1 = nb1, a2 = nb2, a3 = nb3, a4 = nb4;
    double bx = nbsh[t * 5 + 0], b1 = nbsh[t * 5 + 1], b2 = nbsh[t * 5 + 2],
           b3 = nbsh[t * 5 + 3], b4 = nbsh[t * 5 + 4];
    double acc = 0.0;
#pragma unroll
    for (int p = 0; p < 5; ++p) {
      double v;
      if (ax <= bx) { v = ax; ax = a1; a1 = a2; a2 = a3; a3 = a4; a4 = 1e300; }
      else          { v = bx; bx = b1; b1 = b2; b2 = b3; b3 = b4; b4 = 1e300; }
      acc += v * v;
    }
    double d = exp(-(acc / 5.0));
    double u = (double)jax_uniform(kd0, kd1, (uint32_t)(b * NTOK + t));
    dens[t] = d + u * 1e-6;
  }
  __syncthreads();

  // P2: dmin over strictly-higher-density tokens (filler = dist_max), split halves
  double vloc = dmaxv;
  if (act) {
    double dn = dens[t];
    for (int m = m0; m < m1; ++m) {
      double r = Db[(size_t)m * NTOK + t];
      if (dens[m] > dn && r < vloc) vloc = r;
    }
  }
  __syncthreads();                 // nbsh free again (merge reads done)
  if (act && half) nbsh[t] = vloc;
  __syncthreads();
  if (tid < NTOK) {
    double v2 = nbsh[t];
    double v = vloc < v2 ? vloc : v2;
    score[t] = v * dens[t];
  }
  __syncthreads();

  // P3: iterative top-49 (ties -> lower index) on wave 0, scores in registers
  if (wid == 0) {
    double s0 = (lane < NTOK) ? score[lane] : -1e300;
    double s1 = score[lane + 64];
    double s2 = score[lane + 128];
    double s3 = (lane + 192 < NTOK) ? score[lane + 192] : -1e300;
    for (int k = 0; k < KCL; ++k) {
      double mv = s0; int mi = lane;
      if (s1 > mv) { mv = s1; mi = lane + 64; }
      if (s2 > mv) { mv = s2; mi = lane + 128; }
      if (s3 > mv) { mv = s3; mi = lane + 192; }
#pragma unroll
      for (int off = 32; off; off >>= 1) {
        double ov = __shfl_down(mv, off); int oi = __shfl_down(mi, off);
        if (ov > mv || (ov == mv && oi < mi)) { mv = ov; mi = oi; }
      }
      mi = __shfl(mi, 0);
      if (lane == 0) center[k] = mi;
      if (mi == lane) s0 = -1e300;
      else if (mi == lane + 64) s1 = -1e300;
      else if (mi == lane + 128) s2 = -1e300;
      else if (mi == lane + 192) s3 = -1e300;
    }
  }
  __syncthreads();

  // P4: assign to nearest center (ties -> lower k), centers self-assign
  if (tid < NTOK) center_of[tid] = -1;
  __syncthreads();
  if (tid < KCL) { center_of[center[tid]] = (short)tid; bkey[tid] = 0ULL; }
  __syncthreads();
  int mycl = 0;
  if (tid < NTOK) {
    double best = 1e300; int bk = 0;
    for (int k = 0; k < KCL; ++k) {
      double d = Db[(size_t)center[k] * NTOK + tid];   // coalesced
      if (d < best) { best = d; bk = k; }
    }
    short co = center_of[tid];
    if (co >= 0) bk = co;
    mycl = bk;
  }
  __syncthreads();

  // P5: representative = per-cluster max of f32 key (k+u), ties -> larger token index
  if (tid < NTOK) {
    float u = jax_uniform(kn0, kn1, (uint32_t)(b * NTOK + tid));
    float keyf = (float)mycl + u;
    unsigned long long key =
        ((unsigned long long)__float_as_uint(keyf) << 8) | (unsigned)tid;
    atomicMax(&bkey[mycl], key);
  }
  __syncthreads();
  if (tid < KCL) out[b * KCL + tid] = (int)(bkey[tid] & 0xFFu);
}

// ---------------- launch ----------------
extern "C" void kernel_launch(void* const* d_in, const int* in_sizes, int n_in,
                              void* d_out, int out_size, void* d_ws, size_t ws_size,
                              hipStream_t stream) {
  const float* x = (const float*)d_in[0];
  int B = in_sizes[0] / (3 * IMG2);           // 256
  double* dist = (double*)d_ws;
  size_t distBytes = (size_t)B * NTOK * NTOK * sizeof(double);
  unsigned long long* dmax = (unsigned long long*)((char*)d_ws + distBytes);
  int* out = (int*)d_out;

  uint32_t kd0, kd1, kn0, kn1;
  tf2x32(0u, 1u, 0u, 0u, &kd0, &kd1);
  tf2x32(0u, 1u, 0u, 1u, &kn0, &kn1);

  hipMemsetAsync(dmax, 0, B * sizeof(unsigned long long), stream);
  k_dist_mfma<<<dim3(8 * 32 * 28), dim3(256), 0, stream>>>(x, dist, dmax);
  k_cluster2<<<dim3(B), dim3(512), 0, stream>>>(dist, dmax, out, kd0, kd1, kn0, kn1, B);
}

// Round 10
// 319.077 us; speedup vs baseline: 2.9913x; 1.1384x over previous
//
#include <hip/hip_runtime.h>
#include <stdint.h>

#define NTOK 196
#define KCL 49
#define IMG 224
#define IMG2 (224*224)
#define KB 64
#define LDP 68   // f32 cols + pad: b32 frag reads 2-way only (free), b128-write aligned

typedef double f64x4 __attribute__((ext_vector_type(4)));

// ---------------- JAX threefry2x32 (20 rounds), host+device ----------------
__host__ __device__ __forceinline__ void tf2x32(uint32_t k0, uint32_t k1,
    uint32_t x0, uint32_t x1, uint32_t* o0, uint32_t* o1) {
  uint32_t ks2 = k0 ^ k1 ^ 0x1BD11BDAu;
#define TFR(r) { x0 += x1; x1 = (x1 << r) | (x1 >> (32 - r)); x1 ^= x0; }
  x0 += k0; x1 += k1;
  TFR(13) TFR(15) TFR(26) TFR(6)
  x0 += k1; x1 += ks2 + 1u;
  TFR(17) TFR(29) TFR(16) TFR(24)
  x0 += ks2; x1 += k0 + 2u;
  TFR(13) TFR(15) TFR(26) TFR(6)
  x0 += k0; x1 += k1 + 3u;
  TFR(17) TFR(29) TFR(16) TFR(24)
  x0 += k1; x1 += ks2 + 4u;
  TFR(13) TFR(15) TFR(26) TFR(6)
  x0 += ks2; x1 += k0 + 5u;
#undef TFR
  *o0 = x0; *o1 = x1;
}

// jax.random.uniform f32 bits, PARTITIONABLE threefry (jax >= 0.5 default)
__device__ __forceinline__ float jax_uniform(uint32_t k0, uint32_t k1, uint32_t j) {
  uint32_t o0, o1;
  tf2x32(k0, k1, 0u, j, &o0, &o1);
  uint32_t bits = o0 ^ o1;
  return __uint_as_float((bits >> 9) | 0x3f800000u) - 1.0f;
}

// ---------------- K0: per-token sum of squares (fp64) ----------------
__global__ void __launch_bounds__(256) k_sq(const float* __restrict__ x,
                                            double* __restrict__ sq, int B) {
  int wave = blockIdx.x * 4 + (threadIdx.x >> 6);
  int lane = threadIdx.x & 63;
  if (wave >= B * NTOK) return;
  int b = wave / NTOK, n = wave % NTOK;
  int p1 = n / 14, p2 = n % 14;
  const float* xb = x + (size_t)b * 3 * IMG2;
  int rowbase = (p1 * 16) * IMG + p2 * 16;
  double acc = 0.0;
#pragma unroll
  for (int q = 0; q < 12; ++q) {
    int f = lane + q * 64;
    int c = f >> 8, h = (f >> 4) & 15, w = f & 15;
    float v = xb[c * IMG2 + rowbase + h * IMG + w];
    acc += (double)v * (double)v;
  }
#pragma unroll
  for (int off = 32; off; off >>= 1) acc += __shfl_down(acc, off);
  if (lane == 0) sq[wave] = acc;
}

// ---------------- K1: f64-MFMA Gram, f32 LDS staging, triangle+mirror -------------
// grid: 8 xcd * 32 batch-groups * 28 triangle-tiles = 7168 blocks of 256
__global__ void __launch_bounds__(256) k_dist_mfma(const float* __restrict__ x,
    const double* __restrict__ sq, double* __restrict__ dist,
    unsigned long long* __restrict__ dmax) {
  int bid = blockIdx.x;
  int xcd = bid & 7;
  int s = bid >> 3;                 // 0..895
  int b = xcd + 8 * (s / 28);
  int t = s % 28;
  int ti = 0, rem = t, rl = 7;
  while (rem >= rl) { rem -= rl; rl--; ti++; }
  int tj = ti + rem;                // ti <= tj
  int n0b = ti * 32, m0b = tj * 32;
  int tid = threadIdx.x;

  __shared__ __align__(16) float As[32][LDP];
  __shared__ __align__(16) float Bs[32][LDP];
  __shared__ int rbN[32], rbM[32];
  __shared__ double prsh[3];
  __shared__ int okf;

  if (tid < 32) {
    int n = n0b + tid; n = n < NTOK ? n : NTOK - 1;
    rbN[tid] = (n / 14) * 16 * IMG + (n % 14) * 16;
  } else if (tid < 64) {
    int m = m0b + (tid - 32); m = m < NTOK ? m : NTOK - 1;
    rbM[tid - 32] = (m / 14) * 16 * IMG + (m % 14) * 16;
  }
  __syncthreads();

  const float* xb = x + (size_t)b * 3 * IMG2;
  int srow = tid >> 3;              // staging row 0..31
  int sfo  = (tid & 7) * 8;         // staging feature offset 0..56
  int rN = rbN[srow], rM = rbM[srow];
  int lane = tid & 63;
  int wid  = tid >> 6;
  int wi = wid >> 1, wj = wid & 1;
  int aq = lane >> 4;
  const float* Ap = &As[0][0];
  const float* Bp = &Bs[0][0];
  int abase = (wi * 16 + (lane & 15)) * LDP + aq;
  int bbase = (wj * 16 + (lane & 15)) * LDP + aq;

#define LOADT(d0,d1,d2,d3,kc) { int f0 = (kc) + sfo;                         \
    int c_ = f0 >> 8, h_ = (f0 >> 4) & 15, w_ = f0 & 15;                     \
    const float* p_ = xb + c_ * IMG2 + h_ * IMG + w_;                        \
    d0 = *(const float4*)(p_ + rN); d1 = *(const float4*)(p_ + rN + 4);      \
    d2 = *(const float4*)(p_ + rM); d3 = *(const float4*)(p_ + rM + 4); }

  f64x4 acc = {0.0, 0.0, 0.0, 0.0};
  f64x4 acc0 = {0.0, 0.0, 0.0, 0.0};
  float4 ca0, ca1, cb0, cb1;
  LOADT(ca0, ca1, cb0, cb1, 0)

#pragma unroll
  for (int tt = 0; tt < 12; ++tt) {
    __syncthreads();                // previous MFMA phase done reading LDS
    *(float4*)&As[srow][sfo]     = ca0;
    *(float4*)&As[srow][sfo + 4] = ca1;
    *(float4*)&Bs[srow][sfo]     = cb0;
    *(float4*)&Bs[srow][sfo + 4] = cb1;
    __syncthreads();                // tile staged
    float4 na0, na1, nb0, nb1;
    if (tt < 11) LOADT(na0, na1, nb0, nb1, (tt + 1) * KB)  // overlap with MFMA
#pragma unroll
    for (int k = 0; k < KB; k += 4) {
      double av = (double)Ap[abase + k];
      double bv = (double)Bp[bbase + k];
      acc = __builtin_amdgcn_mfma_f64_16x16x4f64(av, bv, acc, 0, 0, 0);
    }
    if (tt == 0) {
      if (wid == 0) {               // layout probe, tile 0 only, wave-parallel
        double q0 = (double)As[0][lane] * (double)Bs[0][lane];
        double q1 = (double)As[1][lane] * (double)Bs[0][lane];
        double q2 = (double)As[4][lane] * (double)Bs[0][lane];
#pragma unroll
        for (int off = 32; off; off >>= 1) {
          q0 += __shfl_down(q0, off);
          q1 += __shfl_down(q1, off);
          q2 += __shfl_down(q2, off);
        }
        if (lane == 0) { prsh[0] = q0; prsh[1] = q1; prsh[2] = q2; }
      }
      acc0 = acc;
    }
    ca0 = na0; ca1 = na1; cb0 = nb0; cb1 = nb1;
  }
#undef LOADT

  if (tid == 0) {
    double tol = 1e-9 * (1.0 + fabs(prsh[0]));
    int ok0  = fabs(prsh[0] - acc0[0]) <= tol;
    int okP1 = ok0 && (fabs(prsh[1] - acc0[1]) <= tol);
    int okP2 = ok0 && (fabs(prsh[2] - acc0[1]) <= tol);
    okf = okP1 ? 1 : (okP2 ? 2 : 0);
  }
  __syncthreads();                  // okf visible; all MFMA reads of As/Bs done
  int mode = okf;

  double (*Dt)[33] = (double(*)[33])(&As[0][0]);  // f64 tile aliases As

  if (mode) {
#pragma unroll
    for (int i = 0; i < 4; ++i) {
      int lr = (mode == 1) ? (aq * 4 + i) : (aq + 4 * i);
      Dt[wi * 16 + lr][wj * 16 + (lane & 15)] = acc[i];
    }
  } else {
    // safety fallback: scalar f64 recompute from f32 LDS staging
    double s00 = 0, s01 = 0, s10 = 0, s11 = 0;
    int ty2 = tid >> 4, tx2 = tid & 15;
    for (int kc = 0; kc < 768; kc += KB) {
      int f0 = kc + sfo;
      int c_ = f0 >> 8, h_ = (f0 >> 4) & 15, w_ = f0 & 15;
      const float* p_ = xb + c_ * IMG2 + h_ * IMG + w_;
      float4 la0 = *(const float4*)(p_ + rN), la1 = *(const float4*)(p_ + rN + 4);
      float4 lb0 = *(const float4*)(p_ + rM), lb1 = *(const float4*)(p_ + rM + 4);
      __syncthreads();
      *(float4*)&As[srow][sfo]     = la0;
      *(float4*)&As[srow][sfo + 4] = la1;
      *(float4*)&Bs[srow][sfo]     = lb0;
      *(float4*)&Bs[srow][sfo + 4] = lb1;
      __syncthreads();
      for (int j = 0; j < KB; ++j) {
        double a0 = (double)As[ty2][j], a1 = (double)As[ty2 + 16][j];
        double b0 = (double)Bs[tx2][j], b1 = (double)Bs[tx2 + 16][j];
        s00 += a0 * b0; s01 += a0 * b1; s10 += a1 * b0; s11 += a1 * b1;
      }
    }
    __syncthreads();
    Dt[ty2][tx2] = s00;       Dt[ty2][tx2 + 16] = s01;
    Dt[ty2 + 16][tx2] = s10;  Dt[ty2 + 16][tx2 + 16] = s11;
  }
  __syncthreads();

  // Phase B: dot -> dist, per-batch max, coalesced writes (+ mirror)
  const double* sqb = sq + b * NTOK;
  const double SQ768 = sqrt(768.0);
  int lr2 = tid >> 3, lc0 = (tid & 7) * 4;
  double dv[4];
  double lmax = 0.0;
#pragma unroll
  for (int j = 0; j < 4; ++j) {
    int n = n0b + lr2, m = m0b + lc0 + j;
    int nn = n < NTOK ? n : NTOK - 1, mm = m < NTOK ? m : NTOK - 1;
    double d2 = sqb[nn] + sqb[mm] - 2.0 * Dt[lr2][lc0 + j];
    double d = sqrt(d2 > 0.0 ? d2 : 0.0) / SQ768;
    dv[j] = d;
    lmax = lmax > d ? lmax : d;
  }
#pragma unroll
  for (int j = 0; j < 4; ++j) Dt[lr2][lc0 + j] = dv[j];  // keep for mirror reads
  double* red = (double*)(&Bs[0][0]);
  red[tid] = lmax;
  __syncthreads();
  for (int st = 128; st; st >>= 1) {
    if (tid < st) { double o = red[tid + st]; if (o > red[tid]) red[tid] = o; }
    __syncthreads();
  }
  if (tid == 0) atomicMax(&dmax[b], (unsigned long long)__double_as_longlong(red[0]));

  double* Db = dist + (size_t)b * NTOK * NTOK;
  {
    int n = n0b + lr2, m0 = m0b + lc0;
    if (n < NTOK && m0 < NTOK) {
      if (m0 + 3 < NTOK) {
        f64x4 v = {dv[0], dv[1], dv[2], dv[3]};
        *(f64x4*)(Db + (size_t)n * NTOK + m0) = v;
      } else {
#pragma unroll
        for (int j = 0; j < 4; ++j)
          if (m0 + j < NTOK) Db[(size_t)n * NTOK + m0 + j] = dv[j];
      }
    }
  }
  if (ti != tj) {                   // mirror: D[m][n] = D[n][m]
    int m = m0b + lr2, n0 = n0b + lc0;
    if (m < NTOK && n0 < NTOK) {
      if (n0 + 3 < NTOK) {
        f64x4 v = {Dt[lc0][lr2], Dt[lc0 + 1][lr2], Dt[lc0 + 2][lr2], Dt[lc0 + 3][lr2]};
        *(f64x4*)(Db + (size_t)m * NTOK + n0) = v;
      } else {
#pragma unroll
        for (int j = 0; j < 4; ++j)
          if (n0 + j < NTOK) Db[(size_t)m * NTOK + n0 + j] = Dt[lc0 + j][lr2];
      }
    }
  }
}

// 5-NN insert (ascending 5-list in registers)
#define INS5(n0_,n1_,n2_,n3_,n4_,v_) {                                        \
  if ((v_) < n4_) { n4_ = (v_);                                               \
    if (n4_ < n3_) { double w_ = n3_; n3_ = n4_; n4_ = w_;                    \
      if (n3_ < n2_) { w_ = n2_; n2_ = n3_; n3_ = w_;                         \
        if (n2_ < n1_) { w_ = n1_; n1_ = n2_; n2_ = w_;                       \
          if (n1_ < n0_) { w_ = n0_; n0_ = n1_; n1_ = w_; } } } } } }

// ---------------- K2: fused clustering, 512 threads, 2-way-split + 2-chain ILP ----
// thread pair (t, t+196) splits each token's m-scan; each thread runs 2 interleaved
// 49-iteration chains. blockIdx == batch keeps XCD affinity with k_dist's writes.
__global__ void __launch_bounds__(512) k_cluster2(const double* __restrict__ dist,
    const unsigned long long* __restrict__ dmax, int* __restrict__ out,
    uint32_t kd0, uint32_t kd1, uint32_t kn0, uint32_t kn1, int B) {
  int b = blockIdx.x;
  int tid = threadIdx.x;
  int lane = tid & 63, wid = tid >> 6;
  const double* Db = dist + (size_t)b * NTOK * NTOK;
  __shared__ double nbsh[NTOK * 5];       // P1 partner lists; reused as partial-min
  __shared__ double dens[NTOK];
  __shared__ double score[NTOK];
  __shared__ int center[KCL];
  __shared__ short center_of[NTOK];
  __shared__ unsigned long long bkey[KCL];
  double dmaxv = __longlong_as_double((long long)dmax[b]);

  int t = (tid < NTOK) ? tid : tid - NTOK;     // token
  int half = (tid < NTOK) ? 0 : 1;             // m-range half
  bool act = tid < 2 * NTOK;
  int m0 = half ? 98 : 0;

  // P1: partial 5-NN over half the row, two interleaved 49-chains (ILP)
  double pa0 = 1e300, pa1 = 1e300, pa2 = 1e300, pa3 = 1e300, pa4 = 1e300;
  double qa0 = 1e300, qa1 = 1e300, qa2 = 1e300, qa3 = 1e300, qa4 = 1e300;
  if (act) {
    const double* base = Db + t;
    for (int i = 0; i < 49; ++i) {
      double v1 = base[(size_t)(m0 + i) * NTOK];        // coalesced (symmetry)
      double v2 = base[(size_t)(m0 + 49 + i) * NTOK];
      INS5(pa0, pa1, pa2, pa3, pa4, v1)
      INS5(qa0, qa1, qa2, qa3, qa4, v2)
    }
  }
  // local merge of the two sorted 5-lists -> this thread's half 5-list
  double nb[5];
  {
    double ax = pa0, a1 = pa1, a2 = pa2, a3 = pa3, a4 = pa4;
    double bx = qa0, b1 = qa1, b2 = qa2, b3 = qa3, b4 = qa4;
#pragma unroll
    for (int p = 0; p < 5; ++p) {
      if (ax <= bx) { nb[p] = ax; ax = a1; a1 = a2; a2 = a3; a3 = a4; a4 = 1e300; }
      else          { nb[p] = bx; bx = b1; b1 = b2; b2 = b3; b3 = b4; b4 = 1e300; }
    }
  }
  if (act && half) {
    nbsh[t * 5 + 0] = nb[0]; nbsh[t * 5 + 1] = nb[1]; nbsh[t * 5 + 2] = nb[2];
    nbsh[t * 5 + 3] = nb[3]; nbsh[t * 5 + 4] = nb[4];
  }
  __syncthreads();
  if (tid < NTOK) {
    // merge with partner's sorted 5-list; sum squares of 5 smallest ascending
    double ax = nb[0], a1 = nb[1], a2 = nb[2], a3 = nb[3], a4 = nb[4];
    double bx = nbsh[t * 5 + 0], b1 = nbsh[t * 5 + 1], b2 = nbsh[t * 5 + 2],
           b3 = nbsh[t * 5 + 3], b4 = nbsh[t * 5 + 4];
    double acc = 0.0;
#pragma unroll
    for (int p = 0; p < 5; ++p) {
      double v;
      if (ax <= bx) { v = ax; ax = a1; a1 = a2; a2 = a3; a3 = a4; a4 = 1e300; }
      else          { v = bx; bx = b1; b1 = b2; b2 = b3; b3 = b4; b4 = 1e300; }
      acc += v * v;
    }
    double d = exp(-(acc / 5.0));
    double u = (double)jax_uniform(kd0, kd1, (uint32_t)(b * NTOK + t));
    dens[t] = d + u * 1e-6;
  }
  __syncthreads();

  // P2: dmin over strictly-higher-density tokens, two interleaved chains
  double vloc = dmaxv;
  if (act) {
    double dn = dens[t];
    const double* base = Db + t;
    double v1 = dmaxv, v2 = dmaxv;
    for (int i = 0; i < 49; ++i) {
      double r1 = base[(size_t)(m0 + i) * NTOK];
      double r2 = base[(size_t)(m0 + 49 + i) * NTOK];
      if (dens[m0 + i] > dn && r1 < v1) v1 = r1;
      if (dens[m0 + 49 + i] > dn && r2 < v2) v2 = r2;
    }
    vloc = v1 < v2 ? v1 : v2;
  }
  __syncthreads();                 // nbsh free again (merge reads done)
  if (act && half) nbsh[t] = vloc;
  __syncthreads();
  if (tid < NTOK) {
    double v2 = nbsh[t];
    double v = vloc < v2 ? vloc : v2;
    score[t] = v * dens[t];
  }
  __syncthreads();

  // P3: iterative top-49 (ties -> lower index) on wave 0, scores in registers
  if (wid == 0) {
    double s0 = (lane < NTOK) ? score[lane] : -1e300;
    double s1 = score[lane + 64];
    double s2 = score[lane + 128];
    double s3 = (lane + 192 < NTOK) ? score[lane + 192] : -1e300;
    for (int k = 0; k < KCL; ++k) {
      double mv = s0; int mi = lane;
      if (s1 > mv) { mv = s1; mi = lane + 64; }
      if (s2 > mv) { mv = s2; mi = lane + 128; }
      if (s3 > mv) { mv = s3; mi = lane + 192; }
#pragma unroll
      for (int off = 32; off; off >>= 1) {
        double ov = __shfl_down(mv, off); int oi = __shfl_down(mi, off);
        if (ov > mv || (ov == mv && oi < mi)) { mv = ov; mi = oi; }
      }
      mi = __shfl(mi, 0);
      if (lane == 0) center[k] = mi;
      if (mi == lane) s0 = -1e300;
      else if (mi == lane + 64) s1 = -1e300;
      else if (mi == lane + 128) s2 = -1e300;
      else if (mi == lane + 192) s3 = -1e300;
    }
  }
  __syncthreads();

  // P4: assign to nearest center (ties -> lower k), centers self-assign
  if (tid < NTOK) center_of[tid] = -1;
  __syncthreads();
  if (tid < KCL) { center_of[center[tid]] = (short)tid; bkey[tid] = 0ULL; }
  __syncthreads();
  int mycl = 0;
  if (tid < NTOK) {
    double best = 1e300; int bk = 0;
    for (int k = 0; k < KCL; ++k) {
      double d = Db[(size_t)center[k] * NTOK + tid];   // coalesced
      if (d < best) { best = d; bk = k; }
    }
    short co = center_of[tid];
    if (co >= 0) bk = co;
    mycl = bk;
  }
  __syncthreads();

  // P5: representative = per-cluster max of f32 key (k+u), ties -> larger token index
  if (tid < NTOK) {
    float u = jax_uniform(kn0, kn1, (uint32_t)(b * NTOK + tid));
    float keyf = (float)mycl + u;
    unsigned long long key =
        ((unsigned long long)__float_as_uint(keyf) << 8) | (unsigned)tid;
    atomicMax(&bkey[mycl], key);
  }
  __syncthreads();
  if (tid < KCL) out[b * KCL + tid] = (int)(bkey[tid] & 0xFFu);
}

// ---------------- launch ----------------
extern "C" void kernel_launch(void* const* d_in, const int* in_sizes, int n_in,
                              void* d_out, int out_size, void* d_ws, size_t ws_size,
                              hipStream_t stream) {
  const float* x = (const float*)d_in[0];
  int B = in_sizes[0] / (3 * IMG2);           // 256
  double* dist = (double*)d_ws;
  size_t distBytes = (size_t)B * NTOK * NTOK * sizeof(double);
  double* sq = (double*)((char*)d_ws + distBytes);
  unsigned long long* dmax =
      (unsigned long long*)((char*)sq + (size_t)B * NTOK * sizeof(double));
  int* out = (int*)d_out;

  uint32_t kd0, kd1, kn0, kn1;
  tf2x32(0u, 1u, 0u, 0u, &kd0, &kd1);
  tf2x32(0u, 1u, 0u, 1u, &kn0, &kn1);

  hipMemsetAsync(dmax, 0, B * sizeof(unsigned long long), stream);
  int totalTok = B * NTOK;
  k_sq<<<dim3((totalTok + 3) / 4), dim3(256), 0, stream>>>(x, sq, B);
  k_dist_mfma<<<dim3(8 * 32 * 28), dim3(256), 0, stream>>>(x, sq, dist, dmax);
  k_cluster2<<<dim3(B), dim3(512), 0, stream>>>(dist, dmax, out, kd0, kd1, kn0, kn1, B);
}

// Round 11
// 303.347 us; speedup vs baseline: 3.1464x; 1.0519x over previous
//
#include <hip/hip_runtime.h>
#include <stdint.h>

#define NTOK 196
#define KCL 49
#define IMG 224
#define IMG2 (224*224)
#define KB 64
#define LDP 68   // f32 cols + pad: b32 frag reads 2-way only (free), b128-write aligned

typedef double f64x4 __attribute__((ext_vector_type(4)));

// ---------------- JAX threefry2x32 (20 rounds), host+device ----------------
__host__ __device__ __forceinline__ void tf2x32(uint32_t k0, uint32_t k1,
    uint32_t x0, uint32_t x1, uint32_t* o0, uint32_t* o1) {
  uint32_t ks2 = k0 ^ k1 ^ 0x1BD11BDAu;
#define TFR(r) { x0 += x1; x1 = (x1 << r) | (x1 >> (32 - r)); x1 ^= x0; }
  x0 += k0; x1 += k1;
  TFR(13) TFR(15) TFR(26) TFR(6)
  x0 += k1; x1 += ks2 + 1u;
  TFR(17) TFR(29) TFR(16) TFR(24)
  x0 += ks2; x1 += k0 + 2u;
  TFR(13) TFR(15) TFR(26) TFR(6)
  x0 += k0; x1 += k1 + 3u;
  TFR(17) TFR(29) TFR(16) TFR(24)
  x0 += k1; x1 += ks2 + 4u;
  TFR(13) TFR(15) TFR(26) TFR(6)
  x0 += ks2; x1 += k0 + 5u;
#undef TFR
  *o0 = x0; *o1 = x1;
}

// jax.random.uniform f32 bits, PARTITIONABLE threefry (jax >= 0.5 default)
__device__ __forceinline__ float jax_uniform(uint32_t k0, uint32_t k1, uint32_t j) {
  uint32_t o0, o1;
  tf2x32(k0, k1, 0u, j, &o0, &o1);
  uint32_t bits = o0 ^ o1;
  return __uint_as_float((bits >> 9) | 0x3f800000u) - 1.0f;
}

// ---------------- K1a: diagonal tiles — Gram + sq from diagonal -------------------
// grid: 8 xcd * 32 batch-groups * 7 diag-tiles = 1792 blocks of 256
__global__ void __launch_bounds__(256) k_diag(const float* __restrict__ x,
    double* __restrict__ sq, double* __restrict__ dist,
    unsigned long long* __restrict__ dmax) {
  int bid = blockIdx.x;
  int xcd = bid & 7;
  int s = bid >> 3;
  int b = xcd + 8 * (s / 7);
  int ti = s % 7;
  int n0b = ti * 32;
  int tid = threadIdx.x;

  __shared__ __align__(16) float As0[32][LDP];
  __shared__ __align__(16) float As1[32][LDP];
  __shared__ int rbN[32];
  __shared__ double prsh[3];
  __shared__ int okf;
  __shared__ double sqN[32];

  if (tid < 32) {
    int n = n0b + tid; n = n < NTOK ? n : NTOK - 1;
    rbN[tid] = (n / 14) * 16 * IMG + (n % 14) * 16;
  }
  __syncthreads();

  const float* xb = x + (size_t)b * 3 * IMG2;
  int srow = tid >> 3;
  int sfo  = (tid & 7) * 8;
  int rN = rbN[srow];
  int lane = tid & 63;
  int wid  = tid >> 6;
  int wi = wid >> 1, wj = wid & 1;
  int aq = lane >> 4;
  const float* A0 = &As0[0][0];
  const float* A1 = &As1[0][0];
  int fragA = (wi * 16 + (lane & 15)) * LDP + aq;
  int fragB = (wj * 16 + (lane & 15)) * LDP + aq;

#define LOADD(d0,d1,kc) { int f0 = (kc) + sfo;                               \
    int c_ = f0 >> 8, h_ = (f0 >> 4) & 15, w_ = f0 & 15;                     \
    const float* p_ = xb + c_ * IMG2 + h_ * IMG + w_;                        \
    d0 = *(const float4*)(p_ + rN); d1 = *(const float4*)(p_ + rN + 4); }

  f64x4 acc = {0.0, 0.0, 0.0, 0.0};
  f64x4 acc0 = {0.0, 0.0, 0.0, 0.0};
  float4 ca0, ca1;
  LOADD(ca0, ca1, 0)
  *(float4*)&As0[srow][sfo]     = ca0;
  *(float4*)&As0[srow][sfo + 4] = ca1;
  LOADD(ca0, ca1, KB)
  __syncthreads();                  // buf0 staged

#pragma unroll
  for (int tt = 0; tt < 12; ++tt) {
    const float* cur = (tt & 1) ? A1 : A0;
    float (*nxt)[LDP] = (tt & 1) ? As0 : As1;
    if (tt < 11) {                  // write tile tt+1 (concurrent w/ MFMA, other buf)
      *(float4*)&nxt[srow][sfo]     = ca0;
      *(float4*)&nxt[srow][sfo + 4] = ca1;
    }
    if (tt < 10) LOADD(ca0, ca1, (tt + 2) * KB)
#pragma unroll
    for (int k = 0; k < KB; k += 4) {
      double av = (double)cur[fragA + k];
      double bv = (double)cur[fragB + k];
      acc = __builtin_amdgcn_mfma_f64_16x16x4f64(av, bv, acc, 0, 0, 0);
    }
    if (tt == 0) {
      if (wid == 0) {               // layout probe on buf0 (tile 0)
        double q0 = (double)A0[0 * LDP + lane] * (double)A0[0 * LDP + lane];
        double q1 = (double)A0[1 * LDP + lane] * (double)A0[0 * LDP + lane];
        double q2 = (double)A0[4 * LDP + lane] * (double)A0[0 * LDP + lane];
#pragma unroll
        for (int off = 32; off; off >>= 1) {
          q0 += __shfl_down(q0, off);
          q1 += __shfl_down(q1, off);
          q2 += __shfl_down(q2, off);
        }
        if (lane == 0) { prsh[0] = q0; prsh[1] = q1; prsh[2] = q2; }
      }
      acc0 = acc;
    }
    __syncthreads();                // single barrier per K-tile
  }
#undef LOADD

  if (tid == 0) {
    double tol = 1e-9 * (1.0 + fabs(prsh[0]));
    int ok0  = fabs(prsh[0] - acc0[0]) <= tol;
    int okP1 = ok0 && (fabs(prsh[1] - acc0[1]) <= tol);
    int okP2 = ok0 && (fabs(prsh[2] - acc0[1]) <= tol);
    okf = okP1 ? 1 : (okP2 ? 2 : 0);
  }
  __syncthreads();
  int mode = okf;

  double (*Dt)[33] = (double(*)[33])A0;

  if (mode) {
#pragma unroll
    for (int i = 0; i < 4; ++i) {
      int lr = (mode == 1) ? (aq * 4 + i) : (aq + 4 * i);
      Dt[wi * 16 + lr][wj * 16 + (lane & 15)] = acc[i];
    }
  } else {
    // fallback: scalar f64 recompute (2-barrier restage into As0)
    double s00 = 0, s01 = 0, s10 = 0, s11 = 0;
    int ty2 = tid >> 4, tx2 = tid & 15;
    for (int kc = 0; kc < 768; kc += KB) {
      int f0 = kc + sfo;
      int c_ = f0 >> 8, h_ = (f0 >> 4) & 15, w_ = f0 & 15;
      const float* p_ = xb + c_ * IMG2 + h_ * IMG + w_;
      float4 la0 = *(const float4*)(p_ + rN), la1 = *(const float4*)(p_ + rN + 4);
      __syncthreads();
      *(float4*)&As0[srow][sfo]     = la0;
      *(float4*)&As0[srow][sfo + 4] = la1;
      __syncthreads();
      for (int j = 0; j < KB; ++j) {
        double a0 = (double)As0[ty2][j], a1 = (double)As0[ty2 + 16][j];
        double b0 = (double)As0[tx2][j], b1 = (double)As0[tx2 + 16][j];
        s00 += a0 * b0; s01 += a0 * b1; s10 += a1 * b0; s11 += a1 * b1;
      }
    }
    __syncthreads();
    Dt[ty2][tx2] = s00;       Dt[ty2][tx2 + 16] = s01;
    Dt[ty2 + 16][tx2] = s10;  Dt[ty2 + 16][tx2 + 16] = s11;
  }
  __syncthreads();

  // sq from Gram diagonal
  if (tid < 32) {
    double v = Dt[tid][tid];
    sqN[tid] = v;
    int n = n0b + tid;
    if (n < NTOK) sq[b * NTOK + n] = v;
  }
  __syncthreads();

  // Phase B: dist, per-batch max, coalesced write (no mirror: ti==tj)
  const double SQ768 = sqrt(768.0);
  int lr2 = tid >> 3, lc0 = (tid & 7) * 4;
  double dv[4];
  double lmax = 0.0;
#pragma unroll
  for (int j = 0; j < 4; ++j) {
    double d2 = sqN[lr2] + sqN[lc0 + j] - 2.0 * Dt[lr2][lc0 + j];
    double d = sqrt(d2 > 0.0 ? d2 : 0.0) / SQ768;
    dv[j] = d;
    lmax = lmax > d ? lmax : d;
  }
  double* red = (double*)A1;
  red[tid] = lmax;
  __syncthreads();
  for (int st = 128; st; st >>= 1) {
    if (tid < st) { double o = red[tid + st]; if (o > red[tid]) red[tid] = o; }
    __syncthreads();
  }
  if (tid == 0) atomicMax(&dmax[b], (unsigned long long)__double_as_longlong(red[0]));

  double* Db = dist + (size_t)b * NTOK * NTOK;
  int n = n0b + lr2, m0 = n0b + lc0;
  if (n < NTOK && m0 < NTOK) {
    if (m0 + 3 < NTOK) {
      f64x4 v = {dv[0], dv[1], dv[2], dv[3]};
      *(f64x4*)(Db + (size_t)n * NTOK + m0) = v;
    } else {
#pragma unroll
      for (int j = 0; j < 4; ++j)
        if (m0 + j < NTOK) Db[(size_t)n * NTOK + m0 + j] = dv[j];
    }
  }
}

// ---------------- K1b: off-diagonal tiles (ti<tj), dbuf, mirror -------------------
// grid: 8 xcd * 32 batch-groups * 21 offdiag-tiles = 5376 blocks of 256
__global__ void __launch_bounds__(256) k_offdiag(const float* __restrict__ x,
    const double* __restrict__ sq, double* __restrict__ dist,
    unsigned long long* __restrict__ dmax) {
  int bid = blockIdx.x;
  int xcd = bid & 7;
  int s = bid >> 3;
  int b = xcd + 8 * (s / 21);
  int t = s % 21;
  int ti = 0, rem = t, rl = 6;
  while (rem >= rl) { rem -= rl; rl--; ti++; }
  int tj = ti + 1 + rem;            // ti < tj
  int n0b = ti * 32, m0b = tj * 32;
  int tid = threadIdx.x;

  __shared__ __align__(16) float As0[32][LDP];
  __shared__ __align__(16) float As1[32][LDP];
  __shared__ __align__(16) float Bs0[32][LDP];
  __shared__ __align__(16) float Bs1[32][LDP];
  __shared__ int rbN[32], rbM[32];
  __shared__ double prsh[3];
  __shared__ int okf;

  if (tid < 32) {
    int n = n0b + tid; n = n < NTOK ? n : NTOK - 1;
    rbN[tid] = (n / 14) * 16 * IMG + (n % 14) * 16;
  } else if (tid < 64) {
    int m = m0b + (tid - 32); m = m < NTOK ? m : NTOK - 1;
    rbM[tid - 32] = (m / 14) * 16 * IMG + (m % 14) * 16;
  }
  __syncthreads();

  const float* xb = x + (size_t)b * 3 * IMG2;
  int srow = tid >> 3;
  int sfo  = (tid & 7) * 8;
  int rN = rbN[srow], rM = rbM[srow];
  int lane = tid & 63;
  int wid  = tid >> 6;
  int wi = wid >> 1, wj = wid & 1;
  int aq = lane >> 4;
  const float* A0 = &As0[0][0];
  const float* A1 = &As1[0][0];
  const float* B0 = &Bs0[0][0];
  const float* B1 = &Bs1[0][0];
  int fragA = (wi * 16 + (lane & 15)) * LDP + aq;
  int fragB = (wj * 16 + (lane & 15)) * LDP + aq;

#define LOADT(d0,d1,d2,d3,kc) { int f0 = (kc) + sfo;                         \
    int c_ = f0 >> 8, h_ = (f0 >> 4) & 15, w_ = f0 & 15;                     \
    const float* p_ = xb + c_ * IMG2 + h_ * IMG + w_;                        \
    d0 = *(const float4*)(p_ + rN); d1 = *(const float4*)(p_ + rN + 4);      \
    d2 = *(const float4*)(p_ + rM); d3 = *(const float4*)(p_ + rM + 4); }

  f64x4 acc = {0.0, 0.0, 0.0, 0.0};
  f64x4 acc0 = {0.0, 0.0, 0.0, 0.0};
  float4 ca0, ca1, cb0, cb1;
  LOADT(ca0, ca1, cb0, cb1, 0)
  *(float4*)&As0[srow][sfo]     = ca0;
  *(float4*)&As0[srow][sfo + 4] = ca1;
  *(float4*)&Bs0[srow][sfo]     = cb0;
  *(float4*)&Bs0[srow][sfo + 4] = cb1;
  LOADT(ca0, ca1, cb0, cb1, KB)
  __syncthreads();                  // buf0 staged

#pragma unroll
  for (int tt = 0; tt < 12; ++tt) {
    const float* curA = (tt & 1) ? A1 : A0;
    const float* curB = (tt & 1) ? B1 : B0;
    float (*nxtA)[LDP] = (tt & 1) ? As0 : As1;
    float (*nxtB)[LDP] = (tt & 1) ? Bs0 : Bs1;
    if (tt < 11) {                  // stage tile tt+1 into other buffer
      *(float4*)&nxtA[srow][sfo]     = ca0;
      *(float4*)&nxtA[srow][sfo + 4] = ca1;
      *(float4*)&nxtB[srow][sfo]     = cb0;
      *(float4*)&nxtB[srow][sfo + 4] = cb1;
    }
    if (tt < 10) LOADT(ca0, ca1, cb0, cb1, (tt + 2) * KB)
#pragma unroll
    for (int k = 0; k < KB; k += 4) {
      double av = (double)curA[fragA + k];
      double bv = (double)curB[fragB + k];
      acc = __builtin_amdgcn_mfma_f64_16x16x4f64(av, bv, acc, 0, 0, 0);
    }
    if (tt == 0) {
      if (wid == 0) {               // layout probe on buf0 (tile 0)
        double q0 = (double)A0[0 * LDP + lane] * (double)B0[0 * LDP + lane];
        double q1 = (double)A0[1 * LDP + lane] * (double)B0[0 * LDP + lane];
        double q2 = (double)A0[4 * LDP + lane] * (double)B0[0 * LDP + lane];
#pragma unroll
        for (int off = 32; off; off >>= 1) {
          q0 += __shfl_down(q0, off);
          q1 += __shfl_down(q1, off);
          q2 += __shfl_down(q2, off);
        }
        if (lane == 0) { prsh[0] = q0; prsh[1] = q1; prsh[2] = q2; }
      }
      acc0 = acc;
    }
    __syncthreads();                // single barrier per K-tile
  }
#undef LOADT

  if (tid == 0) {
    double tol = 1e-9 * (1.0 + fabs(prsh[0]));
    int ok0  = fabs(prsh[0] - acc0[0]) <= tol;
    int okP1 = ok0 && (fabs(prsh[1] - acc0[1]) <= tol);
    int okP2 = ok0 && (fabs(prsh[2] - acc0[1]) <= tol);
    okf = okP1 ? 1 : (okP2 ? 2 : 0);
  }
  __syncthreads();
  int mode = okf;

  double (*Dt)[33] = (double(*)[33])A0;

  if (mode) {
#pragma unroll
    for (int i = 0; i < 4; ++i) {
      int lr = (mode == 1) ? (aq * 4 + i) : (aq + 4 * i);
      Dt[wi * 16 + lr][wj * 16 + (lane & 15)] = acc[i];
    }
  } else {
    // fallback: scalar f64 recompute (2-barrier restage into As0/Bs0)
    double s00 = 0, s01 = 0, s10 = 0, s11 = 0;
    int ty2 = tid >> 4, tx2 = tid & 15;
    for (int kc = 0; kc < 768; kc += KB) {
      int f0 = kc + sfo;
      int c_ = f0 >> 8, h_ = (f0 >> 4) & 15, w_ = f0 & 15;
      const float* p_ = xb + c_ * IMG2 + h_ * IMG + w_;
      float4 la0 = *(const float4*)(p_ + rN), la1 = *(const float4*)(p_ + rN + 4);
      float4 lb0 = *(const float4*)(p_ + rM), lb1 = *(const float4*)(p_ + rM + 4);
      __syncthreads();
      *(float4*)&As0[srow][sfo]     = la0;
      *(float4*)&As0[srow][sfo + 4] = la1;
      *(float4*)&Bs0[srow][sfo]     = lb0;
      *(float4*)&Bs0[srow][sfo + 4] = lb1;
      __syncthreads();
      for (int j = 0; j < KB; ++j) {
        double a0 = (double)As0[ty2][j], a1 = (double)As0[ty2 + 16][j];
        double b0 = (double)Bs0[tx2][j], b1 = (double)Bs0[tx2 + 16][j];
        s00 += a0 * b0; s01 += a0 * b1; s10 += a1 * b0; s11 += a1 * b1;
      }
    }
    __syncthreads();
    Dt[ty2][tx2] = s00;       Dt[ty2][tx2 + 16] = s01;
    Dt[ty2 + 16][tx2] = s10;  Dt[ty2 + 16][tx2 + 16] = s11;
  }
  __syncthreads();

  // Phase B: dist, per-batch max, coalesced writes + mirror
  const double* sqb = sq + b * NTOK;
  const double SQ768 = sqrt(768.0);
  int lr2 = tid >> 3, lc0 = (tid & 7) * 4;
  double dv[4];
  double lmax = 0.0;
#pragma unroll
  for (int j = 0; j < 4; ++j) {
    int n = n0b + lr2, m = m0b + lc0 + j;
    int nn = n < NTOK ? n : NTOK - 1, mm = m < NTOK ? m : NTOK - 1;
    double d2 = sqb[nn] + sqb[mm] - 2.0 * Dt[lr2][lc0 + j];
    double d = sqrt(d2 > 0.0 ? d2 : 0.0) / SQ768;
    dv[j] = d;
    lmax = lmax > d ? lmax : d;
  }
#pragma unroll
  for (int j = 0; j < 4; ++j) Dt[lr2][lc0 + j] = dv[j];  // keep for mirror reads
  double* red = (double*)B0;
  red[tid] = lmax;
  __syncthreads();
  for (int st = 128; st; st >>= 1) {
    if (tid < st) { double o = red[tid + st]; if (o > red[tid]) red[tid] = o; }
    __syncthreads();
  }
  if (tid == 0) atomicMax(&dmax[b], (unsigned long long)__double_as_longlong(red[0]));

  double* Db = dist + (size_t)b * NTOK * NTOK;
  {
    int n = n0b + lr2, m0 = m0b + lc0;
    if (n < NTOK && m0 < NTOK) {
      if (m0 + 3 < NTOK) {
        f64x4 v = {dv[0], dv[1], dv[2], dv[3]};
        *(f64x4*)(Db + (size_t)n * NTOK + m0) = v;
      } else {
#pragma unroll
        for (int j = 0; j < 4; ++j)
          if (m0 + j < NTOK) Db[(size_t)n * NTOK + m0 + j] = dv[j];
      }
    }
  }
  {                                 // mirror: D[m][n] = D[n][m]
    int m = m0b + lr2, n0 = n0b + lc0;
    if (m < NTOK && n0 < NTOK) {
      if (n0 + 3 < NTOK) {
        f64x4 v = {Dt[lc0][lr2], Dt[lc0 + 1][lr2], Dt[lc0 + 2][lr2], Dt[lc0 + 3][lr2]};
        *(f64x4*)(Db + (size_t)m * NTOK + n0) = v;
      } else {
#pragma unroll
        for (int j = 0; j < 4; ++j)
          if (n0 + j < NTOK) Db[(size_t)m * NTOK + n0 + j] = Dt[lc0 + j][lr2];
      }
    }
  }
}

// 5-NN insert (ascending 5-list in registers)
#define INS5(n0_,n1_,n2_,n3_,n4_,v_) {                                        \
  if ((v_) < n4_) { n4_ = (v_);                                               \
    if (n4_ < n3_) { double w_ = n3_; n3_ = n4_; n4_ = w_;                    \
      if (n3_ < n2_) { w_ = n2_; n2_ = n3_; n3_ = w_;                         \
        if (n2_ < n1_) { w_ = n1_; n1_ = n2_; n2_ = w_;                       \
          if (n1_ < n0_) { w_ = n0_; n0_ = n1_; n1_ = w_; } } } } } }

// ---------------- K2: fused clustering, 512 threads, 2-way-split + 2-chain ILP ----
__global__ void __launch_bounds__(512) k_cluster2(const double* __restrict__ dist,
    const unsigned long long* __restrict__ dmax, int* __restrict__ out,
    uint32_t kd0, uint32_t kd1, uint32_t kn0, uint32_t kn1, int B) {
  int b = blockIdx.x;
  int tid = threadIdx.x;
  int lane = tid & 63, wid = tid >> 6;
  const double* Db = dist + (size_t)b * NTOK * NTOK;
  __shared__ double nbsh[NTOK * 5];
  __shared__ double dens[NTOK];
  __shared__ double score[NTOK];
  __shared__ int center[KCL];
  __shared__ short center_of[NTOK];
  __shared__ unsigned long long bkey[KCL];
  double dmaxv = __longlong_as_double((long long)dmax[b]);

  int t = (tid < NTOK) ? tid : tid - NTOK;
  int half = (tid < NTOK) ? 0 : 1;
  bool act = tid < 2 * NTOK;
  int m0 = half ? 98 : 0;

  // P1: partial 5-NN over half the row, two interleaved 49-chains (ILP)
  double pa0 = 1e300, pa1 = 1e300, pa2 = 1e300, pa3 = 1e300, pa4 = 1e300;
  double qa0 = 1e300, qa1 = 1e300, qa2 = 1e300, qa3 = 1e300, qa4 = 1e300;
  if (act) {
    const double* base = Db + t;
    for (int i = 0; i < 49; ++i) {
      double v1 = base[(size_t)(m0 + i) * NTOK];
      double v2 = base[(size_t)(m0 + 49 + i) * NTOK];
      INS5(pa0, pa1, pa2, pa3, pa4, v1)
      INS5(qa0, qa1, qa2, qa3, qa4, v2)
    }
  }
  double nb[5];
  {
    double ax = pa0, a1 = pa1, a2 = pa2, a3 = pa3, a4 = pa4;
    double bx = qa0, b1 = qa1, b2 = qa2, b3 = qa3, b4 = qa4;
#pragma unroll
    for (int p = 0; p < 5; ++p) {
      if (ax <= bx) { nb[p] = ax; ax = a1; a1 = a2; a2 = a3; a3 = a4; a4 = 1e300; }
      else          { nb[p] = bx; bx = b1; b1 = b2; b2 = b3; b3 = b4; b4 = 1e300; }
    }
  }
  if (act && half) {
    nbsh[t * 5 + 0] = nb[0]; nbsh[t * 5 + 1] = nb[1]; nbsh[t * 5 + 2] = nb[2];
    nbsh[t * 5 + 3] = nb[3]; nbsh[t * 5 + 4] = nb[4];
  }
  __syncthreads();
  if (tid < NTOK) {
    double ax = nb[0], a1 = nb[1], a2 = nb[2], a3 = nb[3], a4 = nb[4];
    double bx = nbsh[t * 5 + 0], b1 = nbsh[t * 5 + 1], b2 = nbsh[t * 5 + 2],
           b3 = nbsh[t * 5 + 3], b4 = nbsh[t * 5 + 4];
    double acc = 0.0;
#pragma unroll
    for (int p = 0; p < 5; ++p) {
      double v;
      if (ax <= bx) { v = ax; ax = a1; a1 = a2; a2 = a3; a3 = a4; a4 = 1e300; }
      else          { v = bx; bx = b1; b1 = b2; b2 = b3; b3 = b4; b4 = 1e300; }
      acc += v * v;
    }
    double d = exp(-(acc / 5.0));
    double u = (double)jax_uniform(kd0, kd1, (uint32_t)(b * NTOK + t));
    dens[t] = d + u * 1e-6;
  }
  __syncthreads();

  // P2: dmin over strictly-higher-density tokens, two interleaved chains
  double vloc = dmaxv;
  if (act) {
    double dn = dens[t];
    const double* base = Db + t;
    double v1 = dmaxv, v2 = dmaxv;
    for (int i = 0; i < 49; ++i) {
      double r1 = base[(size_t)(m0 + i) * NTOK];
      double r2 = base[(size_t)(m0 + 49 + i) * NTOK];
      if (dens[m0 + i] > dn && r1 < v1) v1 = r1;
      if (dens[m0 + 49 + i] > dn && r2 < v2) v2 = r2;
    }
    vloc = v1 < v2 ? v1 : v2;
  }
  __syncthreads();
  if (act && half) nbsh[t] = vloc;
  __syncthreads();
  if (tid < NTOK) {
    double v2 = nbsh[t];
    double v = vloc < v2 ? vloc : v2;
    score[t] = v * dens[t];
  }
  __syncthreads();

  // P3: iterative top-49 (ties -> lower index) on wave 0, scores in registers
  if (wid == 0) {
    double s0 = (lane < NTOK) ? score[lane] : -1e300;
    double s1 = score[lane + 64];
    double s2 = score[lane + 128];
    double s3 = (lane + 192 < NTOK) ? score[lane + 192] : -1e300;
    for (int k = 0; k < KCL; ++k) {
      double mv = s0; int mi = lane;
      if (s1 > mv) { mv = s1; mi = lane + 64; }
      if (s2 > mv) { mv = s2; mi = lane + 128; }
      if (s3 > mv) { mv = s3; mi = lane + 192; }
#pragma unroll
      for (int off = 32; off; off >>= 1) {
        double ov = __shfl_down(mv, off); int oi = __shfl_down(mi, off);
        if (ov > mv || (ov == mv && oi < mi)) { mv = ov; mi = oi; }
      }
      mi = __shfl(mi, 0);
      if (lane == 0) center[k] = mi;
      if (mi == lane) s0 = -1e300;
      else if (mi == lane + 64) s1 = -1e300;
      else if (mi == lane + 128) s2 = -1e300;
      else if (mi == lane + 192) s3 = -1e300;
    }
  }
  __syncthreads();

  // P4: assign to nearest center (ties -> lower k), centers self-assign
  if (tid < NTOK) center_of[tid] = -1;
  __syncthreads();
  if (tid < KCL) { center_of[center[tid]] = (short)tid; bkey[tid] = 0ULL; }
  __syncthreads();
  int mycl = 0;
  if (tid < NTOK) {
    double best = 1e300; int bk = 0;
    for (int k = 0; k < KCL; ++k) {
      double d = Db[(size_t)center[k] * NTOK + tid];
      if (d < best) { best = d; bk = k; }
    }
    short co = center_of[tid];
    if (co >= 0) bk = co;
    mycl = bk;
  }
  __syncthreads();

  // P5: representative = per-cluster max of f32 key (k+u), ties -> larger token index
  if (tid < NTOK) {
    float u = jax_uniform(kn0, kn1, (uint32_t)(b * NTOK + tid));
    float keyf = (float)mycl + u;
    unsigned long long key =
        ((unsigned long long)__float_as_uint(keyf) << 8) | (unsigned)tid;
    atomicMax(&bkey[mycl], key);
  }
  __syncthreads();
  if (tid < KCL) out[b * KCL + tid] = (int)(bkey[tid] & 0xFFu);
}

// ---------------- launch ----------------
extern "C" void kernel_launch(void* const* d_in, const int* in_sizes, int n_in,
                              void* d_out, int out_size, void* d_ws, size_t ws_size,
                              hipStream_t stream) {
  const float* x = (const float*)d_in[0];
  int B = in_sizes[0] / (3 * IMG2);           // 256
  double* dist = (double*)d_ws;
  size_t distBytes = (size_t)B * NTOK * NTOK * sizeof(double);
  double* sq = (double*)((char*)d_ws + distBytes);
  unsigned long long* dmax =
      (unsigned long long*)((char*)sq + (size_t)B * NTOK * sizeof(double));
  int* out = (int*)d_out;

  uint32_t kd0, kd1, kn0, kn1;
  tf2x32(0u, 1u, 0u, 0u, &kd0, &kd1);
  tf2x32(0u, 1u, 0u, 1u, &kn0, &kn1);

  hipMemsetAsync(dmax, 0, B * sizeof(unsigned long long), stream);
  k_diag<<<dim3(8 * 32 * 7), dim3(256), 0, stream>>>(x, sq, dist, dmax);
  k_offdiag<<<dim3(8 * 32 * 21), dim3(256), 0, stream>>>(x, sq, dist, dmax);
  k_cluster2<<<dim3(B), dim3(512), 0, stream>>>(dist, dmax, out, kd0, kd1, kn0, kn1, B);
}

// Round 12
// 293.605 us; speedup vs baseline: 3.2508x; 1.0332x over previous
//
#include <hip/hip_runtime.h>
#include <stdint.h>

#define NTOK 196
#define KCL 49
#define IMG 224
#define IMG2 (224*224)
#define KB 64
#define LDP 68   // f32 cols + pad

typedef double f64x4 __attribute__((ext_vector_type(4)));

// ---------------- JAX threefry2x32 (20 rounds), host+device ----------------
__host__ __device__ __forceinline__ void tf2x32(uint32_t k0, uint32_t k1,
    uint32_t x0, uint32_t x1, uint32_t* o0, uint32_t* o1) {
  uint32_t ks2 = k0 ^ k1 ^ 0x1BD11BDAu;
#define TFR(r) { x0 += x1; x1 = (x1 << r) | (x1 >> (32 - r)); x1 ^= x0; }
  x0 += k0; x1 += k1;
  TFR(13) TFR(15) TFR(26) TFR(6)
  x0 += k1; x1 += ks2 + 1u;
  TFR(17) TFR(29) TFR(16) TFR(24)
  x0 += ks2; x1 += k0 + 2u;
  TFR(13) TFR(15) TFR(26) TFR(6)
  x0 += k0; x1 += k1 + 3u;
  TFR(17) TFR(29) TFR(16) TFR(24)
  x0 += k1; x1 += ks2 + 4u;
  TFR(13) TFR(15) TFR(26) TFR(6)
  x0 += ks2; x1 += k0 + 5u;
#undef TFR
  *o0 = x0; *o1 = x1;
}

// jax.random.uniform f32 bits, PARTITIONABLE threefry (jax >= 0.5 default)
__device__ __forceinline__ float jax_uniform(uint32_t k0, uint32_t k1, uint32_t j) {
  uint32_t o0, o1;
  tf2x32(k0, k1, 0u, j, &o0, &o1);
  uint32_t bits = o0 ^ o1;
  return __uint_as_float((bits >> 9) | 0x3f800000u) - 1.0f;
}

// ---------------- K1a: diagonal tiles — Gram + sq from diagonal (R10 staging) -----
// grid: 8 xcd * 32 batch-groups * 7 diag-tiles = 1792 blocks of 256
__global__ void __launch_bounds__(256) k_diag(const float* __restrict__ x,
    double* __restrict__ sq, double* __restrict__ dist,
    unsigned long long* __restrict__ dmax) {
  int bid = blockIdx.x;
  int xcd = bid & 7;
  int s = bid >> 3;
  int b = xcd + 8 * (s / 7);
  int ti = s % 7;
  int n0b = ti * 32;
  int tid = threadIdx.x;

  __shared__ __align__(16) float As[32][LDP];
  __shared__ int rbN[32];
  __shared__ double prsh[3];
  __shared__ int okf;
  __shared__ double sqN[32];
  __shared__ double red2[256];

  if (tid < 32) {
    int n = n0b + tid; n = n < NTOK ? n : NTOK - 1;
    rbN[tid] = (n / 14) * 16 * IMG + (n % 14) * 16;
  }
  __syncthreads();

  const float* xb = x + (size_t)b * 3 * IMG2;
  int srow = tid >> 3;
  int sfo  = (tid & 7) * 8;
  int rN = rbN[srow];
  int lane = tid & 63;
  int wid  = tid >> 6;
  int wi = wid >> 1, wj = wid & 1;
  int aq = lane >> 4;
  const float* A0 = &As[0][0];
  int fragA = (wi * 16 + (lane & 15)) * LDP + aq;
  int fragB = (wj * 16 + (lane & 15)) * LDP + aq;

#define LOADD(d0,d1,kc) { int f0 = (kc) + sfo;                               \
    int c_ = f0 >> 8, h_ = (f0 >> 4) & 15, w_ = f0 & 15;                     \
    const float* p_ = xb + c_ * IMG2 + h_ * IMG + w_;                        \
    d0 = *(const float4*)(p_ + rN); d1 = *(const float4*)(p_ + rN + 4); }

  f64x4 acc = {0.0, 0.0, 0.0, 0.0};
  f64x4 acc0 = {0.0, 0.0, 0.0, 0.0};
  float4 ca0, ca1;
  LOADD(ca0, ca1, 0)

#pragma unroll
  for (int tt = 0; tt < 12; ++tt) {
    __syncthreads();                // prev MFMA done reading LDS
    *(float4*)&As[srow][sfo]     = ca0;
    *(float4*)&As[srow][sfo + 4] = ca1;
    __syncthreads();                // staged
    float4 na0, na1;
    if (tt < 11) LOADD(na0, na1, (tt + 1) * KB)
#pragma unroll
    for (int k = 0; k < KB; k += 4) {
      double av = (double)A0[fragA + k];
      double bv = (double)A0[fragB + k];
      acc = __builtin_amdgcn_mfma_f64_16x16x4f64(av, bv, acc, 0, 0, 0);
    }
    if (tt == 0) {
      if (wid == 0) {               // layout probe (A·A), tile 0
        double q0 = (double)As[0][lane] * (double)As[0][lane];
        double q1 = (double)As[1][lane] * (double)As[0][lane];
        double q2 = (double)As[4][lane] * (double)As[0][lane];
#pragma unroll
        for (int off = 32; off; off >>= 1) {
          q0 += __shfl_down(q0, off);
          q1 += __shfl_down(q1, off);
          q2 += __shfl_down(q2, off);
        }
        if (lane == 0) { prsh[0] = q0; prsh[1] = q1; prsh[2] = q2; }
      }
      acc0 = acc;
    }
    ca0 = na0; ca1 = na1;
  }
#undef LOADD

  if (tid == 0) {
    double tol = 1e-9 * (1.0 + fabs(prsh[0]));
    int ok0  = fabs(prsh[0] - acc0[0]) <= tol;
    int okP1 = ok0 && (fabs(prsh[1] - acc0[1]) <= tol);
    int okP2 = ok0 && (fabs(prsh[2] - acc0[1]) <= tol);
    okf = okP1 ? 1 : (okP2 ? 2 : 0);
  }
  __syncthreads();
  int mode = okf;

  double (*Dt)[33] = (double(*)[33])A0;

  if (mode) {
#pragma unroll
    for (int i = 0; i < 4; ++i) {
      int lr = (mode == 1) ? (aq * 4 + i) : (aq + 4 * i);
      Dt[wi * 16 + lr][wj * 16 + (lane & 15)] = acc[i];
    }
  } else {
    // fallback: scalar f64 recompute
    double s00 = 0, s01 = 0, s10 = 0, s11 = 0;
    int ty2 = tid >> 4, tx2 = tid & 15;
    for (int kc = 0; kc < 768; kc += KB) {
      int f0 = kc + sfo;
      int c_ = f0 >> 8, h_ = (f0 >> 4) & 15, w_ = f0 & 15;
      const float* p_ = xb + c_ * IMG2 + h_ * IMG + w_;
      float4 la0 = *(const float4*)(p_ + rN), la1 = *(const float4*)(p_ + rN + 4);
      __syncthreads();
      *(float4*)&As[srow][sfo]     = la0;
      *(float4*)&As[srow][sfo + 4] = la1;
      __syncthreads();
      for (int j = 0; j < KB; ++j) {
        double a0 = (double)As[ty2][j], a1 = (double)As[ty2 + 16][j];
        double b0 = (double)As[tx2][j], b1 = (double)As[tx2 + 16][j];
        s00 += a0 * b0; s01 += a0 * b1; s10 += a1 * b0; s11 += a1 * b1;
      }
    }
    __syncthreads();
    Dt[ty2][tx2] = s00;       Dt[ty2][tx2 + 16] = s01;
    Dt[ty2 + 16][tx2] = s10;  Dt[ty2 + 16][tx2 + 16] = s11;
  }
  __syncthreads();

  // sq from Gram diagonal
  if (tid < 32) {
    double v = Dt[tid][tid];
    sqN[tid] = v;
    int n = n0b + tid;
    if (n < NTOK) sq[b * NTOK + n] = v;
  }
  __syncthreads();

  // Phase B: dist, per-batch max, coalesced write (no mirror)
  const double SQ768 = sqrt(768.0);
  int lr2 = tid >> 3, lc0 = (tid & 7) * 4;
  double dv[4];
  double lmax = 0.0;
#pragma unroll
  for (int j = 0; j < 4; ++j) {
    double d2 = sqN[lr2] + sqN[lc0 + j] - 2.0 * Dt[lr2][lc0 + j];
    double d = sqrt(d2 > 0.0 ? d2 : 0.0) / SQ768;
    dv[j] = d;
    lmax = lmax > d ? lmax : d;
  }
  red2[tid] = lmax;
  __syncthreads();
  for (int st = 128; st; st >>= 1) {
    if (tid < st) { double o = red2[tid + st]; if (o > red2[tid]) red2[tid] = o; }
    __syncthreads();
  }
  if (tid == 0) atomicMax(&dmax[b], (unsigned long long)__double_as_longlong(red2[0]));

  double* Db = dist + (size_t)b * NTOK * NTOK;
  int n = n0b + lr2, m0 = n0b + lc0;
  if (n < NTOK && m0 < NTOK) {
    if (m0 + 3 < NTOK) {
      f64x4 v = {dv[0], dv[1], dv[2], dv[3]};
      *(f64x4*)(Db + (size_t)n * NTOK + m0) = v;
    } else {
#pragma unroll
      for (int j = 0; j < 4; ++j)
        if (m0 + j < NTOK) Db[(size_t)n * NTOK + m0 + j] = dv[j];
    }
  }
}

// ---------------- K1b: off-diagonal tiles (ti<tj), R10 staging, mirror ------------
// grid: 8 xcd * 32 batch-groups * 21 offdiag-tiles = 5376 blocks of 256
__global__ void __launch_bounds__(256) k_offdiag(const float* __restrict__ x,
    const double* __restrict__ sq, double* __restrict__ dist,
    unsigned long long* __restrict__ dmax) {
  int bid = blockIdx.x;
  int xcd = bid & 7;
  int s = bid >> 3;
  int b = xcd + 8 * (s / 21);
  int t = s % 21;
  int ti = 0, rem = t, rl = 6;
  while (rem >= rl) { rem -= rl; rl--; ti++; }
  int tj = ti + 1 + rem;            // ti < tj
  int n0b = ti * 32, m0b = tj * 32;
  int tid = threadIdx.x;

  __shared__ __align__(16) float As[32][LDP];
  __shared__ __align__(16) float Bs[32][LDP];
  __shared__ int rbN[32], rbM[32];
  __shared__ double prsh[3];
  __shared__ int okf;

  if (tid < 32) {
    int n = n0b + tid; n = n < NTOK ? n : NTOK - 1;
    rbN[tid] = (n / 14) * 16 * IMG + (n % 14) * 16;
  } else if (tid < 64) {
    int m = m0b + (tid - 32); m = m < NTOK ? m : NTOK - 1;
    rbM[tid - 32] = (m / 14) * 16 * IMG + (m % 14) * 16;
  }
  __syncthreads();

  const float* xb = x + (size_t)b * 3 * IMG2;
  int srow = tid >> 3;
  int sfo  = (tid & 7) * 8;
  int rN = rbN[srow], rM = rbM[srow];
  int lane = tid & 63;
  int wid  = tid >> 6;
  int wi = wid >> 1, wj = wid & 1;
  int aq = lane >> 4;
  const float* Ap = &As[0][0];
  const float* Bp = &Bs[0][0];
  int fragA = (wi * 16 + (lane & 15)) * LDP + aq;
  int fragB = (wj * 16 + (lane & 15)) * LDP + aq;

#define LOADT(d0,d1,d2,d3,kc) { int f0 = (kc) + sfo;                         \
    int c_ = f0 >> 8, h_ = (f0 >> 4) & 15, w_ = f0 & 15;                     \
    const float* p_ = xb + c_ * IMG2 + h_ * IMG + w_;                        \
    d0 = *(const float4*)(p_ + rN); d1 = *(const float4*)(p_ + rN + 4);      \
    d2 = *(const float4*)(p_ + rM); d3 = *(const float4*)(p_ + rM + 4); }

  f64x4 acc = {0.0, 0.0, 0.0, 0.0};
  f64x4 acc0 = {0.0, 0.0, 0.0, 0.0};
  float4 ca0, ca1, cb0, cb1;
  LOADT(ca0, ca1, cb0, cb1, 0)

#pragma unroll
  for (int tt = 0; tt < 12; ++tt) {
    __syncthreads();
    *(float4*)&As[srow][sfo]     = ca0;
    *(float4*)&As[srow][sfo + 4] = ca1;
    *(float4*)&Bs[srow][sfo]     = cb0;
    *(float4*)&Bs[srow][sfo + 4] = cb1;
    __syncthreads();
    float4 na0, na1, nb0, nb1;
    if (tt < 11) LOADT(na0, na1, nb0, nb1, (tt + 1) * KB)
#pragma unroll
    for (int k = 0; k < KB; k += 4) {
      double av = (double)Ap[fragA + k];
      double bv = (double)Bp[fragB + k];
      acc = __builtin_amdgcn_mfma_f64_16x16x4f64(av, bv, acc, 0, 0, 0);
    }
    if (tt == 0) {
      if (wid == 0) {
        double q0 = (double)As[0][lane] * (double)Bs[0][lane];
        double q1 = (double)As[1][lane] * (double)Bs[0][lane];
        double q2 = (double)As[4][lane] * (double)Bs[0][lane];
#pragma unroll
        for (int off = 32; off; off >>= 1) {
          q0 += __shfl_down(q0, off);
          q1 += __shfl_down(q1, off);
          q2 += __shfl_down(q2, off);
        }
        if (lane == 0) { prsh[0] = q0; prsh[1] = q1; prsh[2] = q2; }
      }
      acc0 = acc;
    }
    ca0 = na0; ca1 = na1; cb0 = nb0; cb1 = nb1;
  }
#undef LOADT

  if (tid == 0) {
    double tol = 1e-9 * (1.0 + fabs(prsh[0]));
    int ok0  = fabs(prsh[0] - acc0[0]) <= tol;
    int okP1 = ok0 && (fabs(prsh[1] - acc0[1]) <= tol);
    int okP2 = ok0 && (fabs(prsh[2] - acc0[1]) <= tol);
    okf = okP1 ? 1 : (okP2 ? 2 : 0);
  }
  __syncthreads();
  int mode = okf;

  double (*Dt)[33] = (double(*)[33])Ap;

  if (mode) {
#pragma unroll
    for (int i = 0; i < 4; ++i) {
      int lr = (mode == 1) ? (aq * 4 + i) : (aq + 4 * i);
      Dt[wi * 16 + lr][wj * 16 + (lane & 15)] = acc[i];
    }
  } else {
    double s00 = 0, s01 = 0, s10 = 0, s11 = 0;
    int ty2 = tid >> 4, tx2 = tid & 15;
    for (int kc = 0; kc < 768; kc += KB) {
      int f0 = kc + sfo;
      int c_ = f0 >> 8, h_ = (f0 >> 4) & 15, w_ = f0 & 15;
      const float* p_ = xb + c_ * IMG2 + h_ * IMG + w_;
      float4 la0 = *(const float4*)(p_ + rN), la1 = *(const float4*)(p_ + rN + 4);
      float4 lb0 = *(const float4*)(p_ + rM), lb1 = *(const float4*)(p_ + rM + 4);
      __syncthreads();
      *(float4*)&As[srow][sfo]     = la0;
      *(float4*)&As[srow][sfo + 4] = la1;
      *(float4*)&Bs[srow][sfo]     = lb0;
      *(float4*)&Bs[srow][sfo + 4] = lb1;
      __syncthreads();
      for (int j = 0; j < KB; ++j) {
        double a0 = (double)As[ty2][j], a1 = (double)As[ty2 + 16][j];
        double b0 = (double)Bs[tx2][j], b1 = (double)Bs[tx2 + 16][j];
        s00 += a0 * b0; s01 += a0 * b1; s10 += a1 * b0; s11 += a1 * b1;
      }
    }
    __syncthreads();
    Dt[ty2][tx2] = s00;       Dt[ty2][tx2 + 16] = s01;
    Dt[ty2 + 16][tx2] = s10;  Dt[ty2 + 16][tx2 + 16] = s11;
  }
  __syncthreads();

  // Phase B: dist, per-batch max, coalesced writes + mirror
  const double* sqb = sq + b * NTOK;
  const double SQ768 = sqrt(768.0);
  int lr2 = tid >> 3, lc0 = (tid & 7) * 4;
  double dv[4];
  double lmax = 0.0;
#pragma unroll
  for (int j = 0; j < 4; ++j) {
    int n = n0b + lr2, m = m0b + lc0 + j;
    int nn = n < NTOK ? n : NTOK - 1, mm = m < NTOK ? m : NTOK - 1;
    double d2 = sqb[nn] + sqb[mm] - 2.0 * Dt[lr2][lc0 + j];
    double d = sqrt(d2 > 0.0 ? d2 : 0.0) / SQ768;
    dv[j] = d;
    lmax = lmax > d ? lmax : d;
  }
#pragma unroll
  for (int j = 0; j < 4; ++j) Dt[lr2][lc0 + j] = dv[j];  // keep for mirror reads
  double* red = (double*)Bp;
  red[tid] = lmax;
  __syncthreads();
  for (int st = 128; st; st >>= 1) {
    if (tid < st) { double o = red[tid + st]; if (o > red[tid]) red[tid] = o; }
    __syncthreads();
  }
  if (tid == 0) atomicMax(&dmax[b], (unsigned long long)__double_as_longlong(red[0]));

  double* Db = dist + (size_t)b * NTOK * NTOK;
  {
    int n = n0b + lr2, m0 = m0b + lc0;
    if (n < NTOK && m0 < NTOK) {
      if (m0 + 3 < NTOK) {
        f64x4 v = {dv[0], dv[1], dv[2], dv[3]};
        *(f64x4*)(Db + (size_t)n * NTOK + m0) = v;
      } else {
#pragma unroll
        for (int j = 0; j < 4; ++j)
          if (m0 + j < NTOK) Db[(size_t)n * NTOK + m0 + j] = dv[j];
      }
    }
  }
  {
    int m = m0b + lr2, n0 = n0b + lc0;
    if (m < NTOK && n0 < NTOK) {
      if (n0 + 3 < NTOK) {
        f64x4 v = {Dt[lc0][lr2], Dt[lc0 + 1][lr2], Dt[lc0 + 2][lr2], Dt[lc0 + 3][lr2]};
        *(f64x4*)(Db + (size_t)m * NTOK + n0) = v;
      } else {
#pragma unroll
        for (int j = 0; j < 4; ++j)
          if (n0 + j < NTOK) Db[(size_t)m * NTOK + n0 + j] = Dt[lc0 + j][lr2];
      }
    }
  }
}

// 5-NN insert (ascending 5-list in registers)
#define INS5(n0_,n1_,n2_,n3_,n4_,v_) {                                        \
  if ((v_) < n4_) { n4_ = (v_);                                               \
    if (n4_ < n3_) { double w_ = n3_; n3_ = n4_; n4_ = w_;                    \
      if (n3_ < n2_) { w_ = n2_; n2_ = n3_; n3_ = w_;                         \
        if (n2_ < n1_) { w_ = n1_; n1_ = n2_; n2_ = w_;                       \
          if (n1_ < n0_) { w_ = n0_; n0_ = n1_; n1_ = w_; } } } } } }

// merge two ascending 5-lists -> 5 smallest (ascending) into a[]
__device__ __forceinline__ void merge5(double a[5], const double b[5]) {
  double o[5];
  double ax = a[0], a1 = a[1], a2 = a[2], a3 = a[3], a4 = a[4];
  double bx = b[0], b1 = b[1], b2 = b[2], b3 = b[3], b4 = b[4];
#pragma unroll
  for (int p = 0; p < 5; ++p) {
    if (ax <= bx) { o[p] = ax; ax = a1; a1 = a2; a2 = a3; a3 = a4; a4 = 1e300; }
    else          { o[p] = bx; bx = b1; b1 = b2; b2 = b3; b3 = b4; b4 = 1e300; }
  }
#pragma unroll
  for (int p = 0; p < 5; ++p) a[p] = o[p];
}

// ---------------- K2: fused clustering, 1024 threads, 4-way m-scan split ----------
// thread (q=tid>>8, t=tid&255): token t, row-quarter q (49 rows each); 16 waves/CU.
__global__ void __launch_bounds__(1024) k_cluster4(const double* __restrict__ dist,
    const unsigned long long* __restrict__ dmax, int* __restrict__ out,
    uint32_t kd0, uint32_t kd1, uint32_t kn0, uint32_t kn1, int B) {
  int b = blockIdx.x;
  int tid = threadIdx.x;
  int lane = tid & 63, wid = tid >> 6;
  int t = tid & 255, q = tid >> 8;
  bool act = t < NTOK;
  int m0 = q * 49;
  const double* Db = dist + (size_t)b * NTOK * NTOK;
  __shared__ double nbsh[2][NTOK][5];     // P1 partner lists; reused as P2 partials
  __shared__ double dens[NTOK];
  __shared__ double score[NTOK];
  __shared__ int center[KCL];
  __shared__ short center_of[NTOK];
  __shared__ unsigned long long bkey[KCL];
  double dmaxv = __longlong_as_double((long long)dmax[b]);

  // P1: partial 5-NN over quarter of the row (coalesced: Db[m][t]==dist[t][m])
  double nb[5] = {1e300, 1e300, 1e300, 1e300, 1e300};
  if (act) {
    const double* base = Db + t;
    for (int i = 0; i < 49; ++i) {
      double v = base[(size_t)(m0 + i) * NTOK];
      INS5(nb[0], nb[1], nb[2], nb[3], nb[4], v)
    }
    if (q == 1) {
#pragma unroll
      for (int p = 0; p < 5; ++p) nbsh[0][t][p] = nb[p];
    } else if (q == 3) {
#pragma unroll
      for (int p = 0; p < 5; ++p) nbsh[1][t][p] = nb[p];
    }
  }
  __syncthreads();
  if (act && q == 2) {             // merge q2+q3 -> nbsh[1]
    double ob[5];
#pragma unroll
    for (int p = 0; p < 5; ++p) ob[p] = nbsh[1][t][p];
    merge5(nb, ob);
#pragma unroll
    for (int p = 0; p < 5; ++p) nbsh[1][t][p] = nb[p];
  }
  __syncthreads();
  if (tid < NTOK) {                // q0: merge own+q1, then +(q2+q3)
    double ob[5];
#pragma unroll
    for (int p = 0; p < 5; ++p) ob[p] = nbsh[0][t][p];
    merge5(nb, ob);
#pragma unroll
    for (int p = 0; p < 5; ++p) ob[p] = nbsh[1][t][p];
    merge5(nb, ob);
    double acc = 0.0;
#pragma unroll
    for (int p = 0; p < 5; ++p) acc += nb[p] * nb[p];   // ascending sum
    double d = exp(-(acc / 5.0));
    double u = (double)jax_uniform(kd0, kd1, (uint32_t)(b * NTOK + t));
    dens[t] = d + u * 1e-6;
  }
  __syncthreads();

  // P2: dmin over strictly-higher-density tokens (filler = dist_max), 4-way split
  double vloc = dmaxv;
  if (act) {
    double dn = dens[t];
    const double* base = Db + t;
    for (int i = 0; i < 49; ++i) {
      double r = base[(size_t)(m0 + i) * NTOK];
      if (dens[m0 + i] > dn && r < vloc) vloc = r;
    }
  }
  __syncthreads();                 // nbsh reads done; reuse as partial-min store
  double* pm = &nbsh[0][0][0];
  if (act && q > 0) pm[(q - 1) * NTOK + t] = vloc;
  __syncthreads();
  if (tid < NTOK) {
    double v = vloc;
    double p1v = pm[t], p2v = pm[NTOK + t], p3v = pm[2 * NTOK + t];
    v = p1v < v ? p1v : v;
    v = p2v < v ? p2v : v;
    v = p3v < v ? p3v : v;
    score[t] = v * dens[t];
  }
  __syncthreads();

  // P3: iterative top-49 (ties -> lower index) on wave 0, scores in registers
  if (wid == 0) {
    double s0 = (lane < NTOK) ? score[lane] : -1e300;
    double s1 = score[lane + 64];
    double s2 = score[lane + 128];
    double s3 = (lane + 192 < NTOK) ? score[lane + 192] : -1e300;
    for (int k = 0; k < KCL; ++k) {
      double mv = s0; int mi = lane;
      if (s1 > mv) { mv = s1; mi = lane + 64; }
      if (s2 > mv) { mv = s2; mi = lane + 128; }
      if (s3 > mv) { mv = s3; mi = lane + 192; }
#pragma unroll
      for (int off = 32; off; off >>= 1) {
        double ov = __shfl_down(mv, off); int oi = __shfl_down(mi, off);
        if (ov > mv || (ov == mv && oi < mi)) { mv = ov; mi = oi; }
      }
      mi = __shfl(mi, 0);
      if (lane == 0) center[k] = mi;
      if (mi == lane) s0 = -1e300;
      else if (mi == lane + 64) s1 = -1e300;
      else if (mi == lane + 128) s2 = -1e300;
      else if (mi == lane + 192) s3 = -1e300;
    }
  }
  __syncthreads();

  // P4: assign to nearest center (ties -> lower k), centers self-assign
  if (tid < NTOK) center_of[tid] = -1;
  __syncthreads();
  if (tid < KCL) { center_of[center[tid]] = (short)tid; bkey[tid] = 0ULL; }
  __syncthreads();
  int mycl = 0;
  if (tid < NTOK) {
    double best = 1e300; int bk = 0;
    for (int k = 0; k < KCL; ++k) {
      double d = Db[(size_t)center[k] * NTOK + tid];
      if (d < best) { best = d; bk = k; }
    }
    short co = center_of[tid];
    if (co >= 0) bk = co;
    mycl = bk;
  }
  __syncthreads();

  // P5: representative = per-cluster max of f32 key (k+u), ties -> larger token index
  if (tid < NTOK) {
    float u = jax_uniform(kn0, kn1, (uint32_t)(b * NTOK + tid));
    float keyf = (float)mycl + u;
    unsigned long long key =
        ((unsigned long long)__float_as_uint(keyf) << 8) | (unsigned)tid;
    atomicMax(&bkey[mycl], key);
  }
  __syncthreads();
  if (tid < KCL) out[b * KCL + tid] = (int)(bkey[tid] & 0xFFu);
}

// ---------------- launch ----------------
extern "C" void kernel_launch(void* const* d_in, const int* in_sizes, int n_in,
                              void* d_out, int out_size, void* d_ws, size_t ws_size,
                              hipStream_t stream) {
  const float* x = (const float*)d_in[0];
  int B = in_sizes[0] / (3 * IMG2);           // 256
  double* dist = (double*)d_ws;
  size_t distBytes = (size_t)B * NTOK * NTOK * sizeof(double);
  double* sq = (double*)((char*)d_ws + distBytes);
  unsigned long long* dmax =
      (unsigned long long*)((char*)sq + (size_t)B * NTOK * sizeof(double));
  int* out = (int*)d_out;

  uint32_t kd0, kd1, kn0, kn1;
  tf2x32(0u, 1u, 0u, 0u, &kd0, &kd1);
  tf2x32(0u, 1u, 0u, 1u, &kn0, &kn1);

  hipMemsetAsync(dmax, 0, B * sizeof(unsigned long long), stream);
  k_diag<<<dim3(8 * 32 * 7), dim3(256), 0, stream>>>(x, sq, dist, dmax);
  k_offdiag<<<dim3(8 * 32 * 21), dim3(256), 0, stream>>>(x, sq, dist, dmax);
  k_cluster4<<<dim3(B), dim3(1024), 0, stream>>>(dist, dmax, out, kd0, kd1, kn0, kn1, B);
}